// Round 3
// baseline (443.997 us; speedup 1.0000x reference)
//
#include <hip/hip_runtime.h>
#include <hip/hip_bf16.h>

#define NEG_SLOPE 0.2f
#define EPSF 1e-16f

__device__ __forceinline__ float bf2f(unsigned short u) {
  union { unsigned int i; float f; } v; v.i = ((unsigned int)u) << 16; return v.f;
}
__device__ __forceinline__ unsigned short f2bf(float f) {
  union { float f; unsigned int i; } v; v.f = f;
  unsigned int r = v.i + 0x7fffu + ((v.i >> 16) & 1u);  // round-nearest-even
  return (unsigned short)(r >> 16);
}

// ---------------- dtype detector: fp32 vs bf16 for the float inputs ----------------
// Even-indexed 16-bit words of a bf16 array are real bf16 values (exp field in a
// narrow band for N(0,1) data). For an fp32 array they are low mantissa halves:
// exp field uniform-random -> ~69% outliers. Count outliers over 4096 words.
__global__ void detect_k(const unsigned short* __restrict__ xw, int* __restrict__ flag) {
  __shared__ int cnt;
  if (threadIdx.x == 0) cnt = 0;
  __syncthreads();
  int local = 0;
  for (int k = 0; k < 16; k++) {
    unsigned short u = xw[(threadIdx.x * 16 + k) << 1];
    int ex = (u >> 7) & 0xFF;
    if (ex >= 0x90 || ex <= 0x40) local++;
  }
  atomicAdd(&cnt, local);
  __syncthreads();
  if (threadIdx.x == 0) *flag = (cnt > 256) ? 1 : 0;  // 1 = inputs are fp32
}

// ---------------- init: zero deg/cursor, benign-fill CSR arrays ----------------
__global__ void init_k(int* __restrict__ deg, int* __restrict__ cursor,
                       int* __restrict__ csr_src, float* __restrict__ csr_alpha,
                       int n, int e) {
  int i = blockIdx.x * blockDim.x + threadIdx.x;
  if (i < n) { deg[i] = 0; cursor[i] = 0; }
  if (i < e) {
    csr_src[i] = 0;
    ((float4*)csr_alpha)[i] = make_float4(-1e9f, -1e9f, -1e9f, -1e9f);
  }
}

// ---------------- weight re-layout: [H][256][32] -> [256][128] f32 ----------------
__global__ void wprep_k(const void* __restrict__ w, const int* __restrict__ flag,
                        float* __restrict__ wf) {
  int i = blockIdx.x * blockDim.x + threadIdx.x;  // f*128 + col
  if (i >= 256 * 128) return;
  int f = i >> 7, col = i & 127;
  int src = ((col >> 5) << 13) + f * 32 + (col & 31);
  wf[i] = (*flag) ? ((const float*)w)[src] : bf2f(((const unsigned short*)w)[src]);
}

// ---------------- att/bias -> canonical fp32 ----------------
__global__ void smallprep_k(const void* __restrict__ att, const void* __restrict__ bias,
                            const int* __restrict__ flag,
                            float* __restrict__ att_f, float* __restrict__ bias_f) {
  int i = threadIdx.x;  // 256 threads
  int f32 = *flag;
  if (i < 256) att_f[i] = f32 ? ((const float*)att)[i] : bf2f(((const unsigned short*)att)[i]);
  if (i < 128) bias_f[i] = f32 ? ((const float*)bias)[i] : bf2f(((const unsigned short*)bias)[i]);
}

// ---------------- h = x @ W  (32 nodes/block, x tile in LDS as f32), h stored bf16 ----
__global__ __launch_bounds__(256) void gemm_h(const void* __restrict__ xv,
                                              const int* __restrict__ flag,
                                              const float* __restrict__ wf,
                                              unsigned short* __restrict__ h, int n) {
  __shared__ float xs[32][256];
  int t = threadIdx.x;
  int n0 = blockIdx.x << 5;
  int isf32 = *flag;  // wave-uniform
  for (int r = 0; r < 4; r++) {
    int idx = (r << 8) + t;        // 0..1023 = node*32 + c8
    int node = idx >> 5;
    int c8 = idx & 31;
    float vals[8];
    if (n0 + node < n) {
      if (isf32) {
        const float* xp = (const float*)xv + (((size_t)(n0 + node)) << 8) + (c8 << 3);
        float4 f0 = *(const float4*)xp;
        float4 f1 = *(const float4*)(xp + 4);
        vals[0] = f0.x; vals[1] = f0.y; vals[2] = f0.z; vals[3] = f0.w;
        vals[4] = f1.x; vals[5] = f1.y; vals[6] = f1.z; vals[7] = f1.w;
      } else {
        const uint4 raw = *(const uint4*)((const unsigned short*)xv +
                                          (((size_t)(n0 + node)) << 8) + (c8 << 3));
        unsigned int u[4] = {raw.x, raw.y, raw.z, raw.w};
#pragma unroll
        for (int q = 0; q < 4; q++) {
          vals[2 * q]     = bf2f((unsigned short)(u[q] & 0xffffu));
          vals[2 * q + 1] = bf2f((unsigned short)(u[q] >> 16));
        }
      }
    } else {
#pragma unroll
      for (int q = 0; q < 8; q++) vals[q] = 0.f;
    }
    *(float4*)&xs[node][c8 << 3]       = make_float4(vals[0], vals[1], vals[2], vals[3]);
    *(float4*)&xs[node][(c8 << 3) + 4] = make_float4(vals[4], vals[5], vals[6], vals[7]);
  }
  __syncthreads();

  int col = t & 127;
  int g = t >> 7;  // 0 or 1
  float acc[16];
#pragma unroll
  for (int k = 0; k < 16; k++) acc[k] = 0.f;

  for (int f = 0; f < 256; f += 4) {
    float w0 = wf[(f + 0) * 128 + col];
    float w1 = wf[(f + 1) * 128 + col];
    float w2 = wf[(f + 2) * 128 + col];
    float w3 = wf[(f + 3) * 128 + col];
#pragma unroll
    for (int k = 0; k < 16; k++) {
      int node = g + 2 * k;
      float4 xvv = *(const float4*)&xs[node][f];   // wave-uniform addr -> LDS broadcast
      acc[k] = fmaf(xvv.x, w0, acc[k]);
      acc[k] = fmaf(xvv.y, w1, acc[k]);
      acc[k] = fmaf(xvv.z, w2, acc[k]);
      acc[k] = fmaf(xvv.w, w3, acc[k]);
    }
  }
#pragma unroll
  for (int k = 0; k < 16; k++) {
    int node = n0 + g + 2 * k;
    if (node < n) h[(((size_t)node) << 7) + col] = f2bf(acc[k]);
  }
}

// ---------------- per-node attention logits ----------------
__global__ void att_reduce(const unsigned short* __restrict__ h,
                           const float* __restrict__ att_f,
                           float* __restrict__ a_src, float* __restrict__ a_dst, int n) {
  int idx = blockIdx.x * blockDim.x + threadIdx.x;  // (node, head)
  if (idx >= (n << 2)) return;
  int node = idx >> 2, head = idx & 3;
  const unsigned short* hp = h + (((size_t)node) << 7) + (head << 5);
  const float* ap = att_f + (head << 6);
  float s = 0.f, d = 0.f;
#pragma unroll
  for (int c = 0; c < 32; c++) {
    float v = bf2f(hp[c]);
    s = fmaf(v, ap[c], s);
    d = fmaf(v, ap[32 + c], d);
  }
  a_src[idx] = s;
  a_dst[idx] = d;
}

// ---------------- degree histogram ----------------
__global__ void hist_k(const int* __restrict__ ei, int* __restrict__ deg, int e, int n) {
  int i = blockIdx.x * blockDim.x + threadIdx.x;
  if (i >= e) return;
  unsigned d = (unsigned)ei[e + i];
  if (d < (unsigned)n) atomicAdd(&deg[d], 1);
}

// ---------------- single-block exclusive scan -> rowptr ----------------
__global__ __launch_bounds__(1024) void scan_k(const int* __restrict__ deg,
                                               int* __restrict__ rowptr, int n) {
  __shared__ int sd[1024];
  __shared__ int s_carry;
  int t = threadIdx.x;
  if (t == 0) s_carry = 0;
  __syncthreads();
  for (int base = 0; base < n; base += 1024) {
    int carry = s_carry;
    int i = base + t;
    int v = (i < n) ? deg[i] : 0;
    sd[t] = v;
    __syncthreads();
#pragma unroll
    for (int ofs = 1; ofs < 1024; ofs <<= 1) {
      int tv = (t >= ofs) ? sd[t - ofs] : 0;
      __syncthreads();
      sd[t] += tv;
      __syncthreads();
    }
    int incl = sd[t];
    if (i < n) rowptr[i] = carry + incl - v;
    int total = sd[1023];
    __syncthreads();
    if (t == 0) s_carry = carry + total;
    __syncthreads();
  }
  if (t == 0) rowptr[n] = s_carry;
}

// ---------------- CSR fill + edge logits (LeakyReLU) ----------------
__global__ void fill_k(const int* __restrict__ ei, const float* __restrict__ a_src,
                       const float* __restrict__ a_dst, const int* __restrict__ rowptr,
                       int* __restrict__ cursor, int* __restrict__ csr_src,
                       float* __restrict__ csr_alpha, int e, int n) {
  int i = blockIdx.x * blockDim.x + threadIdx.x;
  if (i >= e) return;
  int s = ei[i], d = ei[e + i];
  if ((unsigned)s >= (unsigned)n || (unsigned)d >= (unsigned)n) return;
  int pos = atomicAdd(&cursor[d], 1);
  int slot = rowptr[d] + pos;
  if ((unsigned)slot >= (unsigned)e) return;
  csr_src[slot] = s;
  float4 as = *(const float4*)&a_src[s << 2];
  float4 ad = *(const float4*)&a_dst[d << 2];
  float4 al;
  al.x = as.x + ad.x; al.y = as.y + ad.y; al.z = as.z + ad.z; al.w = as.w + ad.w;
  al.x = al.x > 0.f ? al.x : NEG_SLOPE * al.x;
  al.y = al.y > 0.f ? al.y : NEG_SLOPE * al.y;
  al.z = al.z > 0.f ? al.z : NEG_SLOPE * al.z;
  al.w = al.w > 0.f ? al.w : NEG_SLOPE * al.w;
  *(float4*)&csr_alpha[slot << 2] = al;
}

// ---------------- per-node softmax + gather-aggregate ----------------
__global__ __launch_bounds__(128) void agg_k(const unsigned short* __restrict__ hfeat,
                                             const int* __restrict__ rowptr,
                                             const int* __restrict__ csr_src,
                                             const float* __restrict__ csr_alpha,
                                             const float* __restrict__ bias_f,
                                             const int* __restrict__ flag,
                                             void* __restrict__ outv, int n) {
  int node = blockIdx.x;
  int t = threadIdx.x;     // 0..127 = output col
  int head = t >> 5;
  int row0 = rowptr[node], row1 = rowptr[node + 1];

  float mx = -1e9f;
  for (int i = row0; i < row1; i++) mx = fmaxf(mx, csr_alpha[(i << 2) + head]);

  __shared__ int s_src[32];
  __shared__ float s_w[32][4];
  float acc = 0.f, ssum = 0.f;
  for (int c0 = row0; c0 < row1; c0 += 32) {
    int cnt = min(32, row1 - c0);
    __syncthreads();
    int j = t & 31;
    if (t < 32 && t < cnt) {
      unsigned s = (unsigned)csr_src[c0 + t];
      s_src[t] = (s < (unsigned)n) ? (int)s : 0;
    }
    if (j < cnt) {
      float arg = csr_alpha[((c0 + j) << 2) + head] - mx;
      arg = fminf(arg, 0.f);
      s_w[j][head] = __expf(arg);
    }
    __syncthreads();
    for (int j2 = 0; j2 < cnt; j2++) {
      float wv = s_w[j2][head];
      ssum += wv;
      acc = fmaf(wv, bf2f(hfeat[(((size_t)(unsigned)s_src[j2]) << 7) + t]), acc);
    }
  }
  float val = acc / (ssum + EPSF) + bias_f[t];
  size_t o = (((size_t)node) << 7) + t;
  if (*flag) ((float*)outv)[o] = val;
  else       ((__hip_bfloat16*)outv)[o] = __float2bfloat16(val);
}

extern "C" void kernel_launch(void* const* d_in, const int* in_sizes, int n_in,
                              void* d_out, int out_size, void* d_ws, size_t ws_size,
                              hipStream_t stream) {
  const void* x    = d_in[0];             // fp32 or bf16 [N,256] (detected)
  const int*  ei   = (const int*)d_in[1]; // int32 [2,E]
  const void* w    = d_in[2];             // [4,256,32]
  const void* att  = d_in[3];             // [4,64]
  const void* bias = d_in[4];             // [128]

  const int n = in_sizes[0] / 256;
  const int e = in_sizes[1] / 2;

  // workspace carve (256B aligned); total ~31.2 MB
  char* p = (char*)d_ws;
  size_t off = 0;
  auto carve = [&](size_t bytes) -> void* {
    void* r = p + off;
    off = (off + bytes + 255) & ~(size_t)255;
    return r;
  };
  int*   flag      = (int*)carve(sizeof(int));
  float* att_f     = (float*)carve(256 * 4);
  float* bias_f    = (float*)carve(128 * 4);
  unsigned short* h = (unsigned short*)carve((size_t)n * 128 * 2);  // 12.8 MB
  float* a_src     = (float*)carve((size_t)n * 4 * 4);
  float* a_dst     = (float*)carve((size_t)n * 4 * 4);
  int*   deg       = (int*)carve((size_t)n * 4);
  int*   rowptr    = (int*)carve((size_t)(n + 1) * 4);
  int*   cursor    = (int*)carve((size_t)n * 4);
  int*   csr_src   = (int*)carve((size_t)e * 4);                    // 3.2 MB
  float* csr_alpha = (float*)carve((size_t)e * 4 * 4);              // 12.8 MB
  float* wf        = (float*)carve((size_t)256 * 128 * 4);          // 128 KB
  (void)ws_size;

  detect_k<<<1, 256, 0, stream>>>((const unsigned short*)x, flag);
  init_k<<<(e + 255) / 256, 256, 0, stream>>>(deg, cursor, csr_src, csr_alpha, n, e);
  wprep_k<<<(256 * 128 + 255) / 256, 256, 0, stream>>>(w, flag, wf);
  smallprep_k<<<1, 256, 0, stream>>>(att, bias, flag, att_f, bias_f);
  gemm_h<<<(n + 31) / 32, 256, 0, stream>>>(x, flag, wf, h, n);
  att_reduce<<<(n * 4 + 255) / 256, 256, 0, stream>>>(h, att_f, a_src, a_dst, n);
  hist_k<<<(e + 255) / 256, 256, 0, stream>>>(ei, deg, e, n);
  scan_k<<<1, 1024, 0, stream>>>(deg, rowptr, n);
  fill_k<<<(e + 255) / 256, 256, 0, stream>>>(ei, a_src, a_dst, rowptr, cursor,
                                              csr_src, csr_alpha, e, n);
  agg_k<<<n, 128, 0, stream>>>(h, rowptr, csr_src, csr_alpha, bias_f, flag, d_out, n);
}

// Round 4
// 426.916 us; speedup vs baseline: 1.0400x; 1.0400x over previous
//
#include <hip/hip_runtime.h>
#include <hip/hip_bf16.h>

#define NEG_SLOPE 0.2f
#define EPSF 1e-16f

__device__ __forceinline__ float bf2f(unsigned short u) {
  union { unsigned int i; float f; } v; v.i = ((unsigned int)u) << 16; return v.f;
}
__device__ __forceinline__ unsigned short f2bf(float f) {
  union { float f; unsigned int i; } v; v.f = f;
  unsigned int r = v.i + 0x7fffu + ((v.i >> 16) & 1u);
  return (unsigned short)(r >> 16);
}
// monotonic float<->uint mapping for atomicMax on signed floats
__device__ __forceinline__ unsigned f2ord(float f) {
  unsigned u = __float_as_uint(f);
  return (u >> 31) ? ~u : (u | 0x80000000u);
}
__device__ __forceinline__ float ord2f(unsigned o) {
  unsigned u = (o >> 31) ? (o & 0x7FFFFFFFu) : ~o;
  return __uint_as_float(u);
}

// ---------------- dtype detector: fp32 vs bf16 ----------------
__global__ void detect_k(const unsigned short* __restrict__ xw, int* __restrict__ flag) {
  __shared__ int cnt;
  if (threadIdx.x == 0) cnt = 0;
  __syncthreads();
  int local = 0;
  for (int k = 0; k < 16; k++) {
    unsigned short u = xw[(threadIdx.x * 16 + k) << 1];
    int ex = (u >> 7) & 0xFF;
    if (ex >= 0x90 || ex <= 0x40) local++;
  }
  atomicAdd(&cnt, local);
  __syncthreads();
  if (threadIdx.x == 0) *flag = (cnt > 256) ? 1 : 0;  // 1 = fp32
}

// ---------------- init: zero deg/cursor, m_ord = ord(-3e38) ----------------
__global__ void init2_k(int* __restrict__ deg, int* __restrict__ cursor,
                        unsigned* __restrict__ m_ord, int n) {
  int i = blockIdx.x * blockDim.x + threadIdx.x;
  if (i < n) { deg[i] = 0; cursor[i] = 0; }
  if (i < (n << 2)) m_ord[i] = f2ord(-3.0e38f);
}

// ---------------- weight re-layout: [H][256][32] -> [256][128] f32 ----------------
__global__ void wprep_k(const void* __restrict__ w, const int* __restrict__ flag,
                        float* __restrict__ wf) {
  int i = blockIdx.x * blockDim.x + threadIdx.x;
  if (i >= 256 * 128) return;
  int f = i >> 7, col = i & 127;
  int src = ((col >> 5) << 13) + f * 32 + (col & 31);
  wf[i] = (*flag) ? ((const float*)w)[src] : bf2f(((const unsigned short*)w)[src]);
}

// ---------------- att/bias -> canonical fp32 ----------------
__global__ void smallprep_k(const void* __restrict__ att, const void* __restrict__ bias,
                            const int* __restrict__ flag,
                            float* __restrict__ att_f, float* __restrict__ bias_f) {
  int i = threadIdx.x;
  int f32 = *flag;
  if (i < 256) att_f[i] = f32 ? ((const float*)att)[i] : bf2f(((const unsigned short*)att)[i]);
  if (i < 128) bias_f[i] = f32 ? ((const float*)bias)[i] : bf2f(((const unsigned short*)bias)[i]);
}

// ---------------- h = x @ W : 64 nodes/block, 4 cols x 8 nodes per thread ----------------
__global__ __launch_bounds__(256) void gemm_h(const void* __restrict__ xv,
                                              const int* __restrict__ flag,
                                              const float* __restrict__ wf,
                                              unsigned short* __restrict__ h, int n) {
  __shared__ float xs[64][256];  // 64 KB
  int t = threadIdx.x;
  int n0 = blockIdx.x << 6;
  int isf32 = *flag;
  // stage 64x256 f32 tile: 4096 float4-chunks, 16/thread
  for (int r = 0; r < 16; r++) {
    int idx = (r << 8) + t;
    int node = idx >> 6;
    int c4 = idx & 63;
    float4 v4;
    if (n0 + node < n) {
      if (isf32) {
        v4 = *((const float4*)xv + ((size_t)(n0 + node) << 6) + c4);
      } else {
        uint2 raw = *((const uint2*)xv + ((size_t)(n0 + node) << 6) + c4);
        v4 = make_float4(bf2f((unsigned short)(raw.x & 0xffffu)),
                         bf2f((unsigned short)(raw.x >> 16)),
                         bf2f((unsigned short)(raw.y & 0xffffu)),
                         bf2f((unsigned short)(raw.y >> 16)));
      }
    } else v4 = make_float4(0.f, 0.f, 0.f, 0.f);
    *(float4*)&xs[node][c4 << 2] = v4;
  }
  __syncthreads();

  int c = (t & 31) << 2;   // 4 cols
  int g = t >> 5;          // node group 0..7
  float acc[8][4];
#pragma unroll
  for (int k = 0; k < 8; k++)
#pragma unroll
    for (int j = 0; j < 4; j++) acc[k][j] = 0.f;

  for (int f = 0; f < 256; f += 4) {
    float4 w0 = *(const float4*)&wf[(f + 0) * 128 + c];
    float4 w1 = *(const float4*)&wf[(f + 1) * 128 + c];
    float4 w2 = *(const float4*)&wf[(f + 2) * 128 + c];
    float4 w3 = *(const float4*)&wf[(f + 3) * 128 + c];
#pragma unroll
    for (int k = 0; k < 8; k++) {
      int node = g + (k << 3);
      float4 x4 = *(const float4*)&xs[node][f];  // half-wave-uniform -> LDS broadcast
      acc[k][0] = fmaf(x4.x, w0.x, acc[k][0]); acc[k][0] = fmaf(x4.y, w1.x, acc[k][0]);
      acc[k][0] = fmaf(x4.z, w2.x, acc[k][0]); acc[k][0] = fmaf(x4.w, w3.x, acc[k][0]);
      acc[k][1] = fmaf(x4.x, w0.y, acc[k][1]); acc[k][1] = fmaf(x4.y, w1.y, acc[k][1]);
      acc[k][1] = fmaf(x4.z, w2.y, acc[k][1]); acc[k][1] = fmaf(x4.w, w3.y, acc[k][1]);
      acc[k][2] = fmaf(x4.x, w0.z, acc[k][2]); acc[k][2] = fmaf(x4.y, w1.z, acc[k][2]);
      acc[k][2] = fmaf(x4.z, w2.z, acc[k][2]); acc[k][2] = fmaf(x4.w, w3.z, acc[k][2]);
      acc[k][3] = fmaf(x4.x, w0.w, acc[k][3]); acc[k][3] = fmaf(x4.y, w1.w, acc[k][3]);
      acc[k][3] = fmaf(x4.z, w2.w, acc[k][3]); acc[k][3] = fmaf(x4.w, w3.w, acc[k][3]);
    }
  }
#pragma unroll
  for (int k = 0; k < 8; k++) {
    int node = n0 + g + (k << 3);
    if (node < n) {
      unsigned p0 = (unsigned)f2bf(acc[k][0]) | ((unsigned)f2bf(acc[k][1]) << 16);
      unsigned p1 = (unsigned)f2bf(acc[k][2]) | ((unsigned)f2bf(acc[k][3]) << 16);
      *(uint2*)(h + (((size_t)node) << 7) + c) = make_uint2(p0, p1);
    }
  }
}

// ---------------- per-node attention logits (vectorized) ----------------
__global__ void att2_k(const unsigned short* __restrict__ h, const float* __restrict__ att_f,
                       float* __restrict__ a_src, float* __restrict__ a_dst, int n) {
  int idx = blockIdx.x * blockDim.x + threadIdx.x;
  if (idx >= (n << 2)) return;
  int node = idx >> 2, head = idx & 3;
  const unsigned short* hp = h + (((size_t)node) << 7) + (head << 5);
  const float* ap = att_f + (head << 6);
  float s = 0.f, d = 0.f;
#pragma unroll
  for (int q = 0; q < 4; q++) {
    uint4 raw = *(const uint4*)(hp + (q << 3));
    unsigned u[4] = {raw.x, raw.y, raw.z, raw.w};
#pragma unroll
    for (int k2 = 0; k2 < 4; k2++) {
      float v0 = bf2f((unsigned short)(u[k2] & 0xffffu));
      float v1 = bf2f((unsigned short)(u[k2] >> 16));
      int cc = (q << 3) + (k2 << 1);
      s = fmaf(v0, ap[cc], s);      s = fmaf(v1, ap[cc + 1], s);
      d = fmaf(v0, ap[32 + cc], d); d = fmaf(v1, ap[33 + cc], d);
    }
  }
  a_src[idx] = s;
  a_dst[idx] = d;
}

// ---------------- degree histogram ----------------
__global__ void hist_k(const int* __restrict__ ei, int* __restrict__ deg, int e, int n) {
  int i = blockIdx.x * blockDim.x + threadIdx.x;
  if (i >= e) return;
  unsigned d = (unsigned)ei[e + i];
  if (d < (unsigned)n) atomicAdd(&deg[d], 1);
}

// ---------------- hierarchical scan ----------------
__global__ __launch_bounds__(1024) void scan1_k(const int* __restrict__ deg,
                                                int* __restrict__ rowptr,
                                                int* __restrict__ bsum, int n) {
  __shared__ int sd[1024];
  int t = threadIdx.x;
  int i = (blockIdx.x << 10) + t;
  int v = (i < n) ? deg[i] : 0;
  sd[t] = v;
  __syncthreads();
  for (int ofs = 1; ofs < 1024; ofs <<= 1) {
    int tv = (t >= ofs) ? sd[t - ofs] : 0;
    __syncthreads();
    sd[t] += tv;
    __syncthreads();
  }
  if (i < n) rowptr[i] = sd[t] - v;
  if (t == 1023) bsum[blockIdx.x] = sd[1023];
}
__global__ __launch_bounds__(1024) void scan2_k(int* __restrict__ bsum, int nb) {
  __shared__ int sd[1024];
  int t = threadIdx.x;
  int v = (t < nb) ? bsum[t] : 0;
  sd[t] = v;
  __syncthreads();
  for (int ofs = 1; ofs < 1024; ofs <<= 1) {
    int tv = (t >= ofs) ? sd[t - ofs] : 0;
    __syncthreads();
    sd[t] += tv;
    __syncthreads();
  }
  if (t < nb) bsum[t] = sd[t] - v;
  if (t == 1023) bsum[nb] = sd[1023];
}
__global__ void scan3_k(int* __restrict__ rowptr, const int* __restrict__ bsum,
                        int n, int nb) {
  int i = blockIdx.x * blockDim.x + threadIdx.x;
  if (i < n) rowptr[i] += bsum[i >> 10];
  if (i == 0) rowptr[n] = bsum[nb];
}

// ---------------- CSR fill + edge logits + per-(dst,head) atomicMax ----------------
__global__ void fill_k(const int* __restrict__ ei, const float* __restrict__ a_src,
                       const float* __restrict__ a_dst, const int* __restrict__ rowptr,
                       int* __restrict__ cursor, int* __restrict__ csr_src,
                       float* __restrict__ csr_alpha, unsigned* __restrict__ m_ord,
                       int e, int n) {
  int i = blockIdx.x * blockDim.x + threadIdx.x;
  if (i >= e) return;
  int s = ei[i], d = ei[e + i];
  if ((unsigned)s >= (unsigned)n || (unsigned)d >= (unsigned)n) return;
  int pos = atomicAdd(&cursor[d], 1);
  int slot = rowptr[d] + pos;
  if ((unsigned)slot >= (unsigned)e) return;
  csr_src[slot] = s;
  float4 as = *(const float4*)&a_src[s << 2];
  float4 ad = *(const float4*)&a_dst[d << 2];
  float4 al;
  al.x = as.x + ad.x; al.y = as.y + ad.y; al.z = as.z + ad.z; al.w = as.w + ad.w;
  al.x = al.x > 0.f ? al.x : NEG_SLOPE * al.x;
  al.y = al.y > 0.f ? al.y : NEG_SLOPE * al.y;
  al.z = al.z > 0.f ? al.z : NEG_SLOPE * al.z;
  al.w = al.w > 0.f ? al.w : NEG_SLOPE * al.w;
  *(float4*)&csr_alpha[slot << 2] = al;
  atomicMax(&m_ord[(d << 2) + 0], f2ord(al.x));
  atomicMax(&m_ord[(d << 2) + 1], f2ord(al.y));
  atomicMax(&m_ord[(d << 2) + 2], f2ord(al.z));
  atomicMax(&m_ord[(d << 2) + 3], f2ord(al.w));
}

// ---------------- wave-per-node softmax + gather-aggregate ----------------
__global__ __launch_bounds__(256) void agg_k(const unsigned short* __restrict__ hfeat,
                                             const int* __restrict__ rowptr,
                                             const int* __restrict__ csr_src,
                                             const float* __restrict__ csr_alpha,
                                             const unsigned* __restrict__ m_ord,
                                             const float* __restrict__ bias_f,
                                             const int* __restrict__ flag,
                                             void* __restrict__ outv, int n) {
  int wave = threadIdx.x >> 6;
  int l = threadIdx.x & 63;
  int node = (blockIdx.x << 2) + wave;
  if (node >= n) return;
  int row0 = rowptr[node], row1 = rowptr[node + 1];
  float mv = ord2f(m_ord[(node << 2) + (l & 3)]);
  int hh = l >> 4;  // head for gather phase (cols 2l,2l+1)
  float acc0 = 0.f, acc1 = 0.f, swacc = 0.f;

  for (int c0 = row0; c0 < row1; c0 += 16) {
    // stage: lane l <-> (slot c0+(l>>2), head l&3); csr_alpha[(c0<<2)+l] is coalesced
    int slot = c0 + (l >> 2);
    float wexp = 0.f;
    if (slot < row1) {
      float a = csr_alpha[(c0 << 2) + l];
      wexp = __expf(fminf(a - mv, 0.f));
    }
    swacc += wexp;
    int srcv = 0;
    if (l < 16 && (c0 + l) < row1) srcv = csr_src[c0 + l];
    int cnt = min(16, row1 - c0);
    if (cnt == 16) {
#pragma unroll
      for (int j = 0; j < 16; j++) {
        float sw = __shfl(wexp, (j << 2) | hh, 64);
        int ss = __shfl(srcv, j, 64);
        unsigned hv = *(const unsigned*)(hfeat + (((size_t)ss) << 7) + (l << 1));
        acc0 = fmaf(sw, bf2f((unsigned short)(hv & 0xffffu)), acc0);
        acc1 = fmaf(sw, bf2f((unsigned short)(hv >> 16)), acc1);
      }
    } else {
      for (int j = 0; j < cnt; j++) {
        float sw = __shfl(wexp, (j << 2) | hh, 64);
        int ss = __shfl(srcv, j, 64);
        unsigned hv = *(const unsigned*)(hfeat + (((size_t)ss) << 7) + (l << 1));
        acc0 = fmaf(sw, bf2f((unsigned short)(hv & 0xffffu)), acc0);
        acc1 = fmaf(sw, bf2f((unsigned short)(hv >> 16)), acc1);
      }
    }
  }
  // per-head exp-sum: reduce over the 16 lanes sharing (l&3)
  for (int m = 4; m < 64; m <<= 1) swacc += __shfl_xor(swacc, m, 64);
  float sumv = __shfl(swacc, hh, 64);  // lane hh holds head hh's total
  float rs = 1.f / (sumv + EPSF);
  float b0 = bias_f[l << 1], b1 = bias_f[(l << 1) + 1];
  float o0 = fmaf(acc0, rs, b0), o1 = fmaf(acc1, rs, b1);
  size_t base = (((size_t)node) << 7) + (l << 1);
  if (*flag) {
    *(float2*)((float*)outv + base) = make_float2(o0, o1);
  } else {
    unsigned pk = (unsigned)f2bf(o0) | ((unsigned)f2bf(o1) << 16);
    *(unsigned*)((unsigned short*)outv + base) = pk;
  }
}

extern "C" void kernel_launch(void* const* d_in, const int* in_sizes, int n_in,
                              void* d_out, int out_size, void* d_ws, size_t ws_size,
                              hipStream_t stream) {
  const void* x    = d_in[0];
  const int*  ei   = (const int*)d_in[1];
  const void* w    = d_in[2];
  const void* att  = d_in[3];
  const void* bias = d_in[4];

  const int n = in_sizes[0] / 256;
  const int e = in_sizes[1] / 2;
  const int nb = (n + 1023) >> 10;

  char* p = (char*)d_ws;
  size_t off = 0;
  auto carve = [&](size_t bytes) -> void* {
    void* r = p + off;
    off = (off + bytes + 255) & ~(size_t)255;
    return r;
  };
  int*      flag   = (int*)carve(sizeof(int));
  float*    att_f  = (float*)carve(256 * 4);
  float*    bias_f = (float*)carve(128 * 4);
  unsigned short* h = (unsigned short*)carve((size_t)n * 128 * 2);  // 12.8 MB
  float*    a_src  = (float*)carve((size_t)n * 4 * 4);
  float*    a_dst  = (float*)carve((size_t)n * 4 * 4);
  int*      deg    = (int*)carve((size_t)n * 4);
  int*      rowptr = (int*)carve((size_t)(n + 1) * 4);
  int*      cursor = (int*)carve((size_t)n * 4);
  unsigned* m_ord  = (unsigned*)carve((size_t)n * 4 * 4);
  int*      bsum   = (int*)carve((size_t)(nb + 1) * 4);
  int*      csr_src   = (int*)carve((size_t)e * 4);
  float*    csr_alpha = (float*)carve((size_t)e * 4 * 4);           // 12.8 MB
  float*    wf     = (float*)carve((size_t)256 * 128 * 4);
  (void)ws_size;

  detect_k<<<1, 256, 0, stream>>>((const unsigned short*)x, flag);
  init2_k<<<(n * 4 + 255) / 256, 256, 0, stream>>>(deg, cursor, m_ord, n);
  wprep_k<<<(256 * 128 + 255) / 256, 256, 0, stream>>>(w, flag, wf);
  smallprep_k<<<1, 256, 0, stream>>>(att, bias, flag, att_f, bias_f);
  gemm_h<<<(n + 63) / 64, 256, 0, stream>>>(x, flag, wf, h, n);
  att2_k<<<(n * 4 + 255) / 256, 256, 0, stream>>>(h, att_f, a_src, a_dst, n);
  hist_k<<<(e + 255) / 256, 256, 0, stream>>>(ei, deg, e, n);
  scan1_k<<<nb, 1024, 0, stream>>>(deg, rowptr, bsum, n);
  scan2_k<<<1, 1024, 0, stream>>>(bsum, nb);
  scan3_k<<<(n + 255) / 256, 256, 0, stream>>>(rowptr, bsum, n, nb);
  fill_k<<<(e + 255) / 256, 256, 0, stream>>>(ei, a_src, a_dst, rowptr, cursor,
                                              csr_src, csr_alpha, m_ord, e, n);
  agg_k<<<(n + 3) / 4, 256, 0, stream>>>(h, rowptr, csr_src, csr_alpha, m_ord,
                                         bias_f, flag, d_out, n);
}

// Round 5
// 326.247 us; speedup vs baseline: 1.3609x; 1.3086x over previous
//
#include <hip/hip_runtime.h>
#include <hip/hip_bf16.h>

#define NEG_SLOPE 0.2f
#define EPSF 1e-16f

__device__ __forceinline__ float bf2f(unsigned short u) {
  union { unsigned int i; float f; } v; v.i = ((unsigned int)u) << 16; return v.f;
}
__device__ __forceinline__ unsigned short f2bf(float f) {
  union { float f; unsigned int i; } v; v.f = f;
  unsigned int r = v.i + 0x7fffu + ((v.i >> 16) & 1u);
  return (unsigned short)(r >> 16);
}

// ---------------- dtype detector: fp32 vs bf16 ----------------
__global__ void detect_k(const unsigned short* __restrict__ xw, int* __restrict__ flag) {
  __shared__ int cnt;
  if (threadIdx.x == 0) cnt = 0;
  __syncthreads();
  int local = 0;
  for (int k = 0; k < 16; k++) {
    unsigned short u = xw[(threadIdx.x * 16 + k) << 1];
    int ex = (u >> 7) & 0xFF;
    if (ex >= 0x90 || ex <= 0x40) local++;
  }
  atomicAdd(&cnt, local);
  __syncthreads();
  if (threadIdx.x == 0) *flag = (cnt > 256) ? 1 : 0;  // 1 = fp32
}

// ---------------- init: zero deg ----------------
__global__ void init_k(int* __restrict__ deg, int n) {
  int i = blockIdx.x * blockDim.x + threadIdx.x;
  if (i < n) deg[i] = 0;
}

// ---------------- weight re-layout: [H][256][32] -> [256][128] f32 ----------------
__global__ void wprep_k(const void* __restrict__ w, const int* __restrict__ flag,
                        float* __restrict__ wf) {
  int i = blockIdx.x * blockDim.x + threadIdx.x;
  if (i >= 256 * 128) return;
  int f = i >> 7, col = i & 127;
  int src = ((col >> 5) << 13) + f * 32 + (col & 31);
  wf[i] = (*flag) ? ((const float*)w)[src] : bf2f(((const unsigned short*)w)[src]);
}

// ---------------- att/bias -> canonical fp32 ----------------
__global__ void smallprep_k(const void* __restrict__ att, const void* __restrict__ bias,
                            const int* __restrict__ flag,
                            float* __restrict__ att_f, float* __restrict__ bias_f) {
  int i = threadIdx.x;
  int f32 = *flag;
  if (i < 256) att_f[i] = f32 ? ((const float*)att)[i] : bf2f(((const unsigned short*)att)[i]);
  if (i < 128) bias_f[i] = f32 ? ((const float*)bias)[i] : bf2f(((const unsigned short*)bias)[i]);
}

// ---------------- h = x @ W : 64 nodes/block, 4 cols x 8 nodes per thread ----------------
__global__ __launch_bounds__(256) void gemm_h(const void* __restrict__ xv,
                                              const int* __restrict__ flag,
                                              const float* __restrict__ wf,
                                              unsigned short* __restrict__ h, int n) {
  __shared__ float xs[64][256];  // 64 KB
  int t = threadIdx.x;
  int n0 = blockIdx.x << 6;
  int isf32 = *flag;
  for (int r = 0; r < 16; r++) {
    int idx = (r << 8) + t;
    int node = idx >> 6;
    int c4 = idx & 63;
    float4 v4;
    if (n0 + node < n) {
      if (isf32) {
        v4 = *((const float4*)xv + ((size_t)(n0 + node) << 6) + c4);
      } else {
        uint2 raw = *((const uint2*)xv + ((size_t)(n0 + node) << 6) + c4);
        v4 = make_float4(bf2f((unsigned short)(raw.x & 0xffffu)),
                         bf2f((unsigned short)(raw.x >> 16)),
                         bf2f((unsigned short)(raw.y & 0xffffu)),
                         bf2f((unsigned short)(raw.y >> 16)));
      }
    } else v4 = make_float4(0.f, 0.f, 0.f, 0.f);
    *(float4*)&xs[node][c4 << 2] = v4;
  }
  __syncthreads();

  int c = (t & 31) << 2;
  int g = t >> 5;
  float acc[8][4];
#pragma unroll
  for (int k = 0; k < 8; k++)
#pragma unroll
    for (int j = 0; j < 4; j++) acc[k][j] = 0.f;

  for (int f = 0; f < 256; f += 4) {
    float4 w0 = *(const float4*)&wf[(f + 0) * 128 + c];
    float4 w1 = *(const float4*)&wf[(f + 1) * 128 + c];
    float4 w2 = *(const float4*)&wf[(f + 2) * 128 + c];
    float4 w3 = *(const float4*)&wf[(f + 3) * 128 + c];
#pragma unroll
    for (int k = 0; k < 8; k++) {
      int node = g + (k << 3);
      float4 x4 = *(const float4*)&xs[node][f];
      acc[k][0] = fmaf(x4.x, w0.x, acc[k][0]); acc[k][0] = fmaf(x4.y, w1.x, acc[k][0]);
      acc[k][0] = fmaf(x4.z, w2.x, acc[k][0]); acc[k][0] = fmaf(x4.w, w3.x, acc[k][0]);
      acc[k][1] = fmaf(x4.x, w0.y, acc[k][1]); acc[k][1] = fmaf(x4.y, w1.y, acc[k][1]);
      acc[k][1] = fmaf(x4.z, w2.y, acc[k][1]); acc[k][1] = fmaf(x4.w, w3.y, acc[k][1]);
      acc[k][2] = fmaf(x4.x, w0.z, acc[k][2]); acc[k][2] = fmaf(x4.y, w1.z, acc[k][2]);
      acc[k][2] = fmaf(x4.z, w2.z, acc[k][2]); acc[k][2] = fmaf(x4.w, w3.z, acc[k][2]);
      acc[k][3] = fmaf(x4.x, w0.w, acc[k][3]); acc[k][3] = fmaf(x4.y, w1.w, acc[k][3]);
      acc[k][3] = fmaf(x4.z, w2.w, acc[k][3]); acc[k][3] = fmaf(x4.w, w3.w, acc[k][3]);
    }
  }
#pragma unroll
  for (int k = 0; k < 8; k++) {
    int node = n0 + g + (k << 3);
    if (node < n) {
      unsigned p0 = (unsigned)f2bf(acc[k][0]) | ((unsigned)f2bf(acc[k][1]) << 16);
      unsigned p1 = (unsigned)f2bf(acc[k][2]) | ((unsigned)f2bf(acc[k][3]) << 16);
      *(uint2*)(h + (((size_t)node) << 7) + c) = make_uint2(p0, p1);
    }
  }
}

// ---------------- per-node attention logits (vectorized) ----------------
__global__ void att2_k(const unsigned short* __restrict__ h, const float* __restrict__ att_f,
                       float* __restrict__ a_src, float* __restrict__ a_dst, int n) {
  int idx = blockIdx.x * blockDim.x + threadIdx.x;
  if (idx >= (n << 2)) return;
  int node = idx >> 2, head = idx & 3;
  const unsigned short* hp = h + (((size_t)node) << 7) + (head << 5);
  const float* ap = att_f + (head << 6);
  float s = 0.f, d = 0.f;
#pragma unroll
  for (int q = 0; q < 4; q++) {
    uint4 raw = *(const uint4*)(hp + (q << 3));
    unsigned u[4] = {raw.x, raw.y, raw.z, raw.w};
#pragma unroll
    for (int k2 = 0; k2 < 4; k2++) {
      float v0 = bf2f((unsigned short)(u[k2] & 0xffffu));
      float v1 = bf2f((unsigned short)(u[k2] >> 16));
      int cc = (q << 3) + (k2 << 1);
      s = fmaf(v0, ap[cc], s);      s = fmaf(v1, ap[cc + 1], s);
      d = fmaf(v0, ap[32 + cc], d); d = fmaf(v1, ap[33 + cc], d);
    }
  }
  a_src[idx] = s;
  a_dst[idx] = d;
}

// ---------------- degree histogram ----------------
__global__ void hist_k(const int* __restrict__ ei, int* __restrict__ deg, int e, int n) {
  int i = blockIdx.x * blockDim.x + threadIdx.x;
  if (i >= e) return;
  unsigned d = (unsigned)ei[e + i];
  if (d < (unsigned)n) atomicAdd(&deg[d], 1);
}

// ---------------- hierarchical scan ----------------
__global__ __launch_bounds__(1024) void scan1_k(const int* __restrict__ deg,
                                                int* __restrict__ rowptr,
                                                int* __restrict__ bsum, int n) {
  __shared__ int sd[1024];
  int t = threadIdx.x;
  int i = (blockIdx.x << 10) + t;
  int v = (i < n) ? deg[i] : 0;
  sd[t] = v;
  __syncthreads();
  for (int ofs = 1; ofs < 1024; ofs <<= 1) {
    int tv = (t >= ofs) ? sd[t - ofs] : 0;
    __syncthreads();
    sd[t] += tv;
    __syncthreads();
  }
  if (i < n) rowptr[i] = sd[t] - v;
  if (t == 1023) bsum[blockIdx.x] = sd[1023];
}
__global__ __launch_bounds__(1024) void scan2_k(int* __restrict__ bsum, int nb) {
  __shared__ int sd[1024];
  int t = threadIdx.x;
  int v = (t < nb) ? bsum[t] : 0;
  sd[t] = v;
  __syncthreads();
  for (int ofs = 1; ofs < 1024; ofs <<= 1) {
    int tv = (t >= ofs) ? sd[t - ofs] : 0;
    __syncthreads();
    sd[t] += tv;
    __syncthreads();
  }
  if (t < nb) bsum[t] = sd[t] - v;
  if (t == 1023) bsum[nb] = sd[1023];
}
__global__ void scan3_k(int* __restrict__ rowptr, const int* __restrict__ bsum,
                        int* __restrict__ cursor, int n, int nb) {
  int i = blockIdx.x * blockDim.x + threadIdx.x;
  if (i < n) {
    int v = rowptr[i] + bsum[i >> 10];
    rowptr[i] = v;
    cursor[i] = v;  // cursor starts at row base -> fill's atomicAdd yields slot directly
  }
  if (i == 0) rowptr[n] = bsum[nb];
}

// ---------------- CSR fill: 4B src scatter only ----------------
__global__ void fill_k(const int* __restrict__ ei, int* __restrict__ cursor,
                       int* __restrict__ csr_src, int e, int n) {
  int i = blockIdx.x * blockDim.x + threadIdx.x;
  if (i >= e) return;
  int s = ei[i];
  unsigned d = (unsigned)ei[e + i];
  if (d >= (unsigned)n) return;
  if ((unsigned)s >= (unsigned)n) s = 0;
  int slot = atomicAdd(&cursor[d], 1);
  if ((unsigned)slot < (unsigned)e) csr_src[slot] = s;
}

// ---------------- wave-per-node online-softmax gather-aggregate ----------------
__global__ __launch_bounds__(256) void agg_k(const unsigned short* __restrict__ hfeat,
                                             const int* __restrict__ rowptr,
                                             const int* __restrict__ csr_src,
                                             const float* __restrict__ a_src,
                                             const float* __restrict__ a_dst,
                                             const float* __restrict__ bias_f,
                                             const int* __restrict__ flag,
                                             void* __restrict__ outv, int n) {
  int wave = threadIdx.x >> 6;
  int l = threadIdx.x & 63;
  int node = (blockIdx.x << 2) + wave;
  if (node >= n) return;
  int row0 = rowptr[node], row1 = rowptr[node + 1];
  int hh = l >> 4;         // head owning cols 2l,2l+1 (gather phase)
  int hq = l & 3;          // head in weight phase (slot l>>2)
  float4 ad4 = *(const float4*)&a_dst[node << 2];  // wave-uniform
  float adq = (hq == 0) ? ad4.x : (hq == 1) ? ad4.y : (hq == 2) ? ad4.z : ad4.w;

  float m_run = -3.0e38f;  // running max for head hq (uniform across 16-lane group)
  float acc0 = 0.f, acc1 = 0.f, swacc = 0.f;

  for (int c0 = row0; c0 < row1; c0 += 16) {
    int cnt = min(16, row1 - c0);
    int srcv = 0;
    if (l < 16 && (c0 + l) < row1) srcv = csr_src[c0 + l];
    int myslot = l >> 2;
    int ss = __shfl(srcv, myslot, 64);
    // logit for (slot myslot, head hq)
    float z = -3.0e38f;
    if (myslot < cnt) {
      float zz = a_src[(ss << 2) + hq] + adq;
      z = zz > 0.f ? zz : NEG_SLOPE * zz;
    }
    // chunk max over the 16 lanes sharing hq
    float cm = z;
    cm = fmaxf(cm, __shfl_xor(cm, 4, 64));
    cm = fmaxf(cm, __shfl_xor(cm, 8, 64));
    cm = fmaxf(cm, __shfl_xor(cm, 16, 64));
    cm = fmaxf(cm, __shfl_xor(cm, 32, 64));
    float m_new = fmaxf(m_run, cm);
    float resc_q = __expf(m_run - m_new);      // <=1; first chunk: exp(-inf)=0 (swacc==0)
    m_run = m_new;
    float wexp = (myslot < cnt) ? __expf(z - m_new) : 0.f;
    swacc = swacc * resc_q + wexp;
    float resc_h = __shfl(resc_q, hh, 64);     // head hh's rescale (lanes 0..3 hold heads 0..3)
    acc0 *= resc_h; acc1 *= resc_h;
    if (cnt == 16) {
#pragma unroll
      for (int j = 0; j < 16; j++) {
        float sw = __shfl(wexp, (j << 2) | hh, 64);
        int sj = __shfl(srcv, j, 64);
        unsigned hv = *(const unsigned*)(hfeat + (((size_t)sj) << 7) + (l << 1));
        acc0 = fmaf(sw, bf2f((unsigned short)(hv & 0xffffu)), acc0);
        acc1 = fmaf(sw, bf2f((unsigned short)(hv >> 16)), acc1);
      }
    } else {
      for (int j = 0; j < cnt; j++) {
        float sw = __shfl(wexp, (j << 2) | hh, 64);
        int sj = __shfl(srcv, j, 64);
        unsigned hv = *(const unsigned*)(hfeat + (((size_t)sj) << 7) + (l << 1));
        acc0 = fmaf(sw, bf2f((unsigned short)(hv & 0xffffu)), acc0);
        acc1 = fmaf(sw, bf2f((unsigned short)(hv >> 16)), acc1);
      }
    }
  }
  // per-head exp-sum across the 16-lane group
  for (int m = 4; m < 64; m <<= 1) swacc += __shfl_xor(swacc, m, 64);
  float sumv = __shfl(swacc, hh, 64);
  float rs = 1.f / (sumv + EPSF);
  float o0 = fmaf(acc0, rs, bias_f[l << 1]);
  float o1 = fmaf(acc1, rs, bias_f[(l << 1) + 1]);
  size_t base = (((size_t)node) << 7) + (l << 1);
  if (*flag) {
    *(float2*)((float*)outv + base) = make_float2(o0, o1);
  } else {
    unsigned pk = (unsigned)f2bf(o0) | ((unsigned)f2bf(o1) << 16);
    *(unsigned*)((unsigned short*)outv + base) = pk;
  }
}

extern "C" void kernel_launch(void* const* d_in, const int* in_sizes, int n_in,
                              void* d_out, int out_size, void* d_ws, size_t ws_size,
                              hipStream_t stream) {
  const void* x    = d_in[0];
  const int*  ei   = (const int*)d_in[1];
  const void* w    = d_in[2];
  const void* att  = d_in[3];
  const void* bias = d_in[4];

  const int n = in_sizes[0] / 256;
  const int e = in_sizes[1] / 2;
  const int nb = (n + 1023) >> 10;

  char* p = (char*)d_ws;
  size_t off = 0;
  auto carve = [&](size_t bytes) -> void* {
    void* r = p + off;
    off = (off + bytes + 255) & ~(size_t)255;
    return r;
  };
  int*      flag   = (int*)carve(sizeof(int));
  float*    att_f  = (float*)carve(256 * 4);
  float*    bias_f = (float*)carve(128 * 4);
  unsigned short* h = (unsigned short*)carve((size_t)n * 128 * 2);  // 12.8 MB
  float*    a_src  = (float*)carve((size_t)n * 4 * 4);
  float*    a_dst  = (float*)carve((size_t)n * 4 * 4);
  int*      deg    = (int*)carve((size_t)n * 4);
  int*      rowptr = (int*)carve((size_t)(n + 1) * 4);
  int*      cursor = (int*)carve((size_t)n * 4);
  int*      bsum   = (int*)carve((size_t)(nb + 1) * 4);
  int*      csr_src = (int*)carve((size_t)e * 4);                   // 3.2 MB
  float*    wf     = (float*)carve((size_t)256 * 128 * 4);
  (void)ws_size;

  detect_k<<<1, 256, 0, stream>>>((const unsigned short*)x, flag);
  init_k<<<(n + 255) / 256, 256, 0, stream>>>(deg, n);
  wprep_k<<<(256 * 128 + 255) / 256, 256, 0, stream>>>(w, flag, wf);
  smallprep_k<<<1, 256, 0, stream>>>(att, bias, flag, att_f, bias_f);
  gemm_h<<<(n + 63) / 64, 256, 0, stream>>>(x, flag, wf, h, n);
  att2_k<<<(n * 4 + 255) / 256, 256, 0, stream>>>(h, att_f, a_src, a_dst, n);
  hist_k<<<(e + 255) / 256, 256, 0, stream>>>(ei, deg, e, n);
  scan1_k<<<nb, 1024, 0, stream>>>(deg, rowptr, bsum, n);
  scan2_k<<<1, 1024, 0, stream>>>(bsum, nb);
  scan3_k<<<(n + 255) / 256, 256, 0, stream>>>(rowptr, bsum, cursor, n, nb);
  fill_k<<<(e + 255) / 256, 256, 0, stream>>>(ei, cursor, csr_src, e, n);
  agg_k<<<(n + 3) / 4, 256, 0, stream>>>(h, rowptr, csr_src, a_src, a_dst,
                                         bias_f, flag, d_out, n);
}

// Round 6
// 293.677 us; speedup vs baseline: 1.5119x; 1.1109x over previous
//
#include <hip/hip_runtime.h>
#include <hip/hip_bf16.h>

#define NEG_SLOPE 0.2f
#define EPSF 1e-16f

typedef __attribute__((ext_vector_type(8))) short short8;     // 8 bf16 = 4 VGPR
typedef __attribute__((ext_vector_type(4))) float floatx4;    // MFMA acc

__device__ __forceinline__ float bf2f(unsigned short u) {
  union { unsigned int i; float f; } v; v.i = ((unsigned int)u) << 16; return v.f;
}
__device__ __forceinline__ unsigned short f2bf(float f) {
  union { float f; unsigned int i; } v; v.f = f;
  unsigned int r = v.i + 0x7fffu + ((v.i >> 16) & 1u);  // RNE
  return (unsigned short)(r >> 16);
}

// ---------------- prep0: dtype detect (block 0) + zero deg (all blocks) ----------------
__global__ void prep0_k(const unsigned short* __restrict__ xw, int* __restrict__ flag,
                        int* __restrict__ deg, int n) {
  int i = blockIdx.x * blockDim.x + threadIdx.x;
  if (i < n) deg[i] = 0;
  if (blockIdx.x == 0) {
    __shared__ int cnt;
    if (threadIdx.x == 0) cnt = 0;
    __syncthreads();
    int local = 0;
    for (int k = 0; k < 16; k++) {
      unsigned short u = xw[(threadIdx.x * 16 + k) << 1];
      int ex = (u >> 7) & 0xFF;
      if (ex >= 0x90 || ex <= 0x40) local++;
    }
    atomicAdd(&cnt, local);
    __syncthreads();
    if (threadIdx.x == 0) *flag = (cnt > 256) ? 1 : 0;  // 1 = fp32 inputs
  }
}

// ---------------- prep1: W -> B-fragment-packed bf16 (blocks 0..127) + att/bias (block 128) ----
// Bpack[((kb*8+nt)*64 + lane)*8 + j] = W[f = kb*32 + (lane>>4)*8 + j][col = nt*16 + (lane&15)]
// W[f][col] = weight[col>>5][f][col&31]
__global__ void prep1_k(const void* __restrict__ w, const void* __restrict__ att,
                        const void* __restrict__ bias, const int* __restrict__ flag,
                        unsigned short* __restrict__ bpack,
                        float* __restrict__ att_f, float* __restrict__ bias_f) {
  int f32 = *flag;
  if (blockIdx.x < 128) {
    int i = blockIdx.x * 256 + threadIdx.x;  // 0..32767
    int j = i & 7, lane = (i >> 3) & 63, nt = (i >> 9) & 7, kb = i >> 12;
    int f = (kb << 5) + ((lane >> 4) << 3) + j;
    int col = (nt << 4) + (lane & 15);
    int src = ((col >> 5) << 13) + (f << 5) + (col & 31);
    float v = f32 ? ((const float*)w)[src] : bf2f(((const unsigned short*)w)[src]);
    bpack[i] = f2bf(v);
  } else {
    int i = threadIdx.x;
    if (i < 256) att_f[i] = f32 ? ((const float*)att)[i] : bf2f(((const unsigned short*)att)[i]);
    if (i < 128) bias_f[i] = f32 ? ((const float*)bias)[i] : bf2f(((const unsigned short*)bias)[i]);
  }
}

// ---------------- h = x @ W via bf16 MFMA: 128 rows/block, wave = 32 rows x 128 cols ----------
__global__ __launch_bounds__(256) void gemm_h(const void* __restrict__ xv,
                                              const int* __restrict__ flag,
                                              const unsigned short* __restrict__ bpack,
                                              unsigned short* __restrict__ h, int n) {
  int t = threadIdx.x;
  int wave = t >> 6, l = t & 63;
  int quad = l >> 4, m16 = l & 15;
  long n0 = (long)blockIdx.x * 128 + wave * 32;
  int isf32 = *flag;

  floatx4 acc[2][8];
#pragma unroll
  for (int mt = 0; mt < 2; mt++)
#pragma unroll
    for (int nt = 0; nt < 8; nt++) acc[mt][nt] = (floatx4){0.f, 0.f, 0.f, 0.f};

  for (int kb = 0; kb < 8; kb++) {
    short8 afr[2];
#pragma unroll
    for (int mt = 0; mt < 2; mt++) {
      long row = n0 + mt * 16 + m16;
      if (row >= n) row = n - 1;  // clamp; result discarded at store
      if (isf32) {
        const float* xp = (const float*)xv + (row << 8) + (kb << 5) + (quad << 3);
        float4 u0 = *(const float4*)xp;
        float4 u1 = *(const float4*)(xp + 4);
        short8 a;
        a[0] = (short)f2bf(u0.x); a[1] = (short)f2bf(u0.y);
        a[2] = (short)f2bf(u0.z); a[3] = (short)f2bf(u0.w);
        a[4] = (short)f2bf(u1.x); a[5] = (short)f2bf(u1.y);
        a[6] = (short)f2bf(u1.z); a[7] = (short)f2bf(u1.w);
        afr[mt] = a;
      } else {
        afr[mt] = *(const short8*)((const unsigned short*)xv + (row << 8) + (kb << 5) + (quad << 3));
      }
    }
#pragma unroll
    for (int nt = 0; nt < 8; nt++) {
      short8 bfr = *(const short8*)(bpack + (((kb << 3) + nt) << 9) + (l << 3));
      acc[0][nt] = __builtin_amdgcn_mfma_f32_16x16x32_bf16(afr[0], bfr, acc[0][nt], 0, 0, 0);
      acc[1][nt] = __builtin_amdgcn_mfma_f32_16x16x32_bf16(afr[1], bfr, acc[1][nt], 0, 0, 0);
    }
  }
  // epilogue: C/D layout col = l&15, row = quad*4 + r
#pragma unroll
  for (int mt = 0; mt < 2; mt++)
#pragma unroll
    for (int r = 0; r < 4; r++) {
      long row = n0 + mt * 16 + quad * 4 + r;
      if (row < n) {
#pragma unroll
        for (int nt = 0; nt < 8; nt++)
          h[(row << 7) + (nt << 4) + m16] = f2bf(acc[mt][nt][r]);
      }
    }
}

// ---------------- per-node attention logits (vectorized) ----------------
__global__ void att2_k(const unsigned short* __restrict__ h, const float* __restrict__ att_f,
                       float* __restrict__ a_src, float* __restrict__ a_dst, int n) {
  int idx = blockIdx.x * blockDim.x + threadIdx.x;
  if (idx >= (n << 2)) return;
  int node = idx >> 2, head = idx & 3;
  const unsigned short* hp = h + (((size_t)node) << 7) + (head << 5);
  const float* ap = att_f + (head << 6);
  float s = 0.f, d = 0.f;
#pragma unroll
  for (int q = 0; q < 4; q++) {
    uint4 raw = *(const uint4*)(hp + (q << 3));
    unsigned u[4] = {raw.x, raw.y, raw.z, raw.w};
#pragma unroll
    for (int k2 = 0; k2 < 4; k2++) {
      float v0 = bf2f((unsigned short)(u[k2] & 0xffffu));
      float v1 = bf2f((unsigned short)(u[k2] >> 16));
      int cc = (q << 3) + (k2 << 1);
      s = fmaf(v0, ap[cc], s);      s = fmaf(v1, ap[cc + 1], s);
      d = fmaf(v0, ap[32 + cc], d); d = fmaf(v1, ap[33 + cc], d);
    }
  }
  a_src[idx] = s;
  a_dst[idx] = d;
}

// ---------------- degree histogram ----------------
__global__ void hist_k(const int* __restrict__ ei, int* __restrict__ deg, int e, int n) {
  int i = blockIdx.x * blockDim.x + threadIdx.x;
  if (i >= e) return;
  unsigned d = (unsigned)ei[e + i];
  if (d < (unsigned)n) atomicAdd(&deg[d], 1);
}

// ---------------- hierarchical scan ----------------
__global__ __launch_bounds__(1024) void scan1_k(const int* __restrict__ deg,
                                                int* __restrict__ rowptr,
                                                int* __restrict__ bsum, int n) {
  __shared__ int sd[1024];
  int t = threadIdx.x;
  int i = (blockIdx.x << 10) + t;
  int v = (i < n) ? deg[i] : 0;
  sd[t] = v;
  __syncthreads();
  for (int ofs = 1; ofs < 1024; ofs <<= 1) {
    int tv = (t >= ofs) ? sd[t - ofs] : 0;
    __syncthreads();
    sd[t] += tv;
    __syncthreads();
  }
  if (i < n) rowptr[i] = sd[t] - v;
  if (t == 1023) bsum[blockIdx.x] = sd[1023];
}
__global__ __launch_bounds__(1024) void scan2_k(int* __restrict__ bsum, int nb) {
  __shared__ int sd[1024];
  int t = threadIdx.x;
  int v = (t < nb) ? bsum[t] : 0;
  sd[t] = v;
  __syncthreads();
  for (int ofs = 1; ofs < 1024; ofs <<= 1) {
    int tv = (t >= ofs) ? sd[t - ofs] : 0;
    __syncthreads();
    sd[t] += tv;
    __syncthreads();
  }
  if (t < nb) bsum[t] = sd[t] - v;
  if (t == 1023) bsum[nb] = sd[1023];
}
__global__ void scan3_k(int* __restrict__ rowptr, const int* __restrict__ bsum,
                        int* __restrict__ cursor, int n, int nb) {
  int i = blockIdx.x * blockDim.x + threadIdx.x;
  if (i < n) {
    int v = rowptr[i] + bsum[i >> 10];
    rowptr[i] = v;
    cursor[i] = v;
  }
  if (i == 0) rowptr[n] = bsum[nb];
}

// ---------------- CSR fill: 4B src scatter only ----------------
__global__ void fill_k(const int* __restrict__ ei, int* __restrict__ cursor,
                       int* __restrict__ csr_src, int e, int n) {
  int i = blockIdx.x * blockDim.x + threadIdx.x;
  if (i >= e) return;
  int s = ei[i];
  unsigned d = (unsigned)ei[e + i];
  if (d >= (unsigned)n) return;
  if ((unsigned)s >= (unsigned)n) s = 0;
  int slot = atomicAdd(&cursor[d], 1);
  if ((unsigned)slot < (unsigned)e) csr_src[slot] = s;
}

// ---------------- wave-per-node online-softmax gather-aggregate ----------------
__global__ __launch_bounds__(256) void agg_k(const unsigned short* __restrict__ hfeat,
                                             const int* __restrict__ rowptr,
                                             const int* __restrict__ csr_src,
                                             const float* __restrict__ a_src,
                                             const float* __restrict__ a_dst,
                                             const float* __restrict__ bias_f,
                                             const int* __restrict__ flag,
                                             void* __restrict__ outv, int n) {
  int wave = threadIdx.x >> 6;
  int l = threadIdx.x & 63;
  int node = (blockIdx.x << 2) + wave;
  if (node >= n) return;
  int row0 = rowptr[node], row1 = rowptr[node + 1];
  int hh = l >> 4;
  int hq = l & 3;
  float4 ad4 = *(const float4*)&a_dst[node << 2];
  float adq = (hq == 0) ? ad4.x : (hq == 1) ? ad4.y : (hq == 2) ? ad4.z : ad4.w;

  float m_run = -3.0e38f;
  float acc0 = 0.f, acc1 = 0.f, swacc = 0.f;

  for (int c0 = row0; c0 < row1; c0 += 16) {
    int cnt = min(16, row1 - c0);
    int srcv = 0;
    if (l < 16 && (c0 + l) < row1) srcv = csr_src[c0 + l];
    int myslot = l >> 2;
    int ss = __shfl(srcv, myslot, 64);
    float z = -3.0e38f;
    if (myslot < cnt) {
      float zz = a_src[(ss << 2) + hq] + adq;
      z = zz > 0.f ? zz : NEG_SLOPE * zz;
    }
    float cm = z;
    cm = fmaxf(cm, __shfl_xor(cm, 4, 64));
    cm = fmaxf(cm, __shfl_xor(cm, 8, 64));
    cm = fmaxf(cm, __shfl_xor(cm, 16, 64));
    cm = fmaxf(cm, __shfl_xor(cm, 32, 64));
    float m_new = fmaxf(m_run, cm);
    float resc_q = __expf(m_run - m_new);
    m_run = m_new;
    float wexp = (myslot < cnt) ? __expf(z - m_new) : 0.f;
    swacc = swacc * resc_q + wexp;
    float resc_h = __shfl(resc_q, hh, 64);
    acc0 *= resc_h; acc1 *= resc_h;
    if (cnt == 16) {
#pragma unroll
      for (int j = 0; j < 16; j++) {
        float sw = __shfl(wexp, (j << 2) | hh, 64);
        int sj = __shfl(srcv, j, 64);
        unsigned hv = *(const unsigned*)(hfeat + (((size_t)sj) << 7) + (l << 1));
        acc0 = fmaf(sw, bf2f((unsigned short)(hv & 0xffffu)), acc0);
        acc1 = fmaf(sw, bf2f((unsigned short)(hv >> 16)), acc1);
      }
    } else {
      for (int j = 0; j < cnt; j++) {
        float sw = __shfl(wexp, (j << 2) | hh, 64);
        int sj = __shfl(srcv, j, 64);
        unsigned hv = *(const unsigned*)(hfeat + (((size_t)sj) << 7) + (l << 1));
        acc0 = fmaf(sw, bf2f((unsigned short)(hv & 0xffffu)), acc0);
        acc1 = fmaf(sw, bf2f((unsigned short)(hv >> 16)), acc1);
      }
    }
  }
  for (int m = 4; m < 64; m <<= 1) swacc += __shfl_xor(swacc, m, 64);
  float sumv = __shfl(swacc, hh, 64);
  float rs = 1.f / (sumv + EPSF);
  float o0 = fmaf(acc0, rs, bias_f[l << 1]);
  float o1 = fmaf(acc1, rs, bias_f[(l << 1) + 1]);
  size_t base = (((size_t)node) << 7) + (l << 1);
  if (*flag) {
    *(float2*)((float*)outv + base) = make_float2(o0, o1);
  } else {
    unsigned pk = (unsigned)f2bf(o0) | ((unsigned)f2bf(o1) << 16);
    *(unsigned*)((unsigned short*)outv + base) = pk;
  }
}

extern "C" void kernel_launch(void* const* d_in, const int* in_sizes, int n_in,
                              void* d_out, int out_size, void* d_ws, size_t ws_size,
                              hipStream_t stream) {
  const void* x    = d_in[0];
  const int*  ei   = (const int*)d_in[1];
  const void* w    = d_in[2];
  const void* att  = d_in[3];
  const void* bias = d_in[4];

  const int n = in_sizes[0] / 256;
  const int e = in_sizes[1] / 2;
  const int nb = (n + 1023) >> 10;

  char* p = (char*)d_ws;
  size_t off = 0;
  auto carve = [&](size_t bytes) -> void* {
    void* r = p + off;
    off = (off + bytes + 255) & ~(size_t)255;
    return r;
  };
  int*      flag   = (int*)carve(sizeof(int));
  float*    att_f  = (float*)carve(256 * 4);
  float*    bias_f = (float*)carve(128 * 4);
  unsigned short* h = (unsigned short*)carve((size_t)n * 128 * 2);   // 12.8 MB
  float*    a_src  = (float*)carve((size_t)n * 4 * 4);
  float*    a_dst  = (float*)carve((size_t)n * 4 * 4);
  int*      deg    = (int*)carve((size_t)n * 4);
  int*      rowptr = (int*)carve((size_t)(n + 1) * 4);
  int*      cursor = (int*)carve((size_t)n * 4);
  int*      bsum   = (int*)carve((size_t)(nb + 1) * 4);
  int*      csr_src = (int*)carve((size_t)e * 4);                    // 3.2 MB
  unsigned short* bpack = (unsigned short*)carve((size_t)256 * 128 * 2);  // 64 KB
  (void)ws_size;

  prep0_k<<<(n + 255) / 256, 256, 0, stream>>>((const unsigned short*)x, flag, deg, n);
  prep1_k<<<129, 256, 0, stream>>>(w, att, bias, flag, bpack, att_f, bias_f);
  gemm_h<<<(n + 127) / 128, 256, 0, stream>>>(x, flag, bpack, h, n);
  att2_k<<<(n * 4 + 255) / 256, 256, 0, stream>>>(h, att_f, a_src, a_dst, n);
  hist_k<<<(e + 255) / 256, 256, 0, stream>>>(ei, deg, e, n);
  scan1_k<<<nb, 1024, 0, stream>>>(deg, rowptr, bsum, n);
  scan2_k<<<1, 1024, 0, stream>>>(bsum, nb);
  scan3_k<<<(n + 255) / 256, 256, 0, stream>>>(rowptr, bsum, cursor, n, nb);
  fill_k<<<(e + 255) / 256, 256, 0, stream>>>(ei, cursor, csr_src, e, n);
  agg_k<<<(n + 3) / 4, 256, 0, stream>>>(h, rowptr, csr_src, a_src, a_dst,
                                         bias_f, flag, d_out, n);
}

// Round 7
// 243.514 us; speedup vs baseline: 1.8233x; 1.2060x over previous
//
#include <hip/hip_runtime.h>
#include <hip/hip_bf16.h>

#define NEG_SLOPE 0.2f
#define EPSF 1e-16f

typedef __attribute__((ext_vector_type(8))) short short8;     // 8 bf16 = 4 VGPR
typedef __attribute__((ext_vector_type(4))) float floatx4;    // MFMA acc

__device__ __forceinline__ float bf2f(unsigned short u) {
  union { unsigned int i; float f; } v; v.i = ((unsigned int)u) << 16; return v.f;
}
__device__ __forceinline__ unsigned short f2bf(float f) {
  union { float f; unsigned int i; } v; v.f = f;
  unsigned int r = v.i + 0x7fffu + ((v.i >> 16) & 1u);  // RNE
  return (unsigned short)(r >> 16);
}

// ---------------- prep0: dtype detect (block 0) + zero deg ----------------
__global__ void prep0_k(const unsigned short* __restrict__ xw, int* __restrict__ flag,
                        int* __restrict__ deg, int n) {
  int i = blockIdx.x * blockDim.x + threadIdx.x;
  if (i < n) deg[i] = 0;
  if (blockIdx.x == 0) {
    __shared__ int cnt;
    if (threadIdx.x == 0) cnt = 0;
    __syncthreads();
    int local = 0;
    for (int k = 0; k < 16; k++) {
      unsigned short u = xw[(threadIdx.x * 16 + k) << 1];
      int ex = (u >> 7) & 0xFF;
      if (ex >= 0x90 || ex <= 0x40) local++;
    }
    atomicAdd(&cnt, local);
    __syncthreads();
    if (threadIdx.x == 0) *flag = (cnt > 256) ? 1 : 0;  // 1 = fp32 inputs
  }
}

// ---------------- fused: hist (blocks < hb) | B-pack + att/bias (blocks >= hb) ----------
__global__ __launch_bounds__(256) void histprep_k(const int* __restrict__ ei,
                                                  int* __restrict__ deg,
                                                  const void* __restrict__ w,
                                                  const void* __restrict__ att,
                                                  const void* __restrict__ bias,
                                                  const int* __restrict__ flag,
                                                  unsigned short* __restrict__ bpack,
                                                  float* __restrict__ att_f,
                                                  float* __restrict__ bias_f,
                                                  int e, int n, int hb) {
  int b = blockIdx.x;
  if (b < hb) {
    int i = b * 256 + threadIdx.x;
    if (i >= e) return;
    unsigned d = (unsigned)ei[e + i];
    if (d < (unsigned)n) atomicAdd(&deg[d], 1);
  } else {
    int f32 = *flag;
    int pb = b - hb;
    if (pb < 128) {
      int i = pb * 256 + threadIdx.x;  // 0..32767
      int j = i & 7, lane = (i >> 3) & 63, nt = (i >> 9) & 7, kb = i >> 12;
      int f = (kb << 5) + ((lane >> 4) << 3) + j;
      int col = (nt << 4) + (lane & 15);
      int src = ((col >> 5) << 13) + (f << 5) + (col & 31);
      float v = f32 ? ((const float*)w)[src] : bf2f(((const unsigned short*)w)[src]);
      bpack[i] = f2bf(v);
    } else {
      int i = threadIdx.x;
      if (i < 256) att_f[i] = f32 ? ((const float*)att)[i] : bf2f(((const unsigned short*)att)[i]);
      if (i < 128) bias_f[i] = f32 ? ((const float*)bias)[i] : bf2f(((const unsigned short*)bias)[i]);
    }
  }
}

// ---------------- hierarchical scan ----------------
__global__ __launch_bounds__(1024) void scan1_k(const int* __restrict__ deg,
                                                int* __restrict__ rowptr,
                                                int* __restrict__ bsum, int n) {
  __shared__ int sd[1024];
  int t = threadIdx.x;
  int i = (blockIdx.x << 10) + t;
  int v = (i < n) ? deg[i] : 0;
  sd[t] = v;
  __syncthreads();
  for (int ofs = 1; ofs < 1024; ofs <<= 1) {
    int tv = (t >= ofs) ? sd[t - ofs] : 0;
    __syncthreads();
    sd[t] += tv;
    __syncthreads();
  }
  if (i < n) rowptr[i] = sd[t] - v;
  if (t == 1023) bsum[blockIdx.x] = sd[1023];
}
__global__ __launch_bounds__(1024) void scan2_k(int* __restrict__ bsum, int nb) {
  __shared__ int sd[1024];
  int t = threadIdx.x;
  int v = (t < nb) ? bsum[t] : 0;
  sd[t] = v;
  __syncthreads();
  for (int ofs = 1; ofs < 1024; ofs <<= 1) {
    int tv = (t >= ofs) ? sd[t - ofs] : 0;
    __syncthreads();
    sd[t] += tv;
    __syncthreads();
  }
  if (t < nb) bsum[t] = sd[t] - v;
  if (t == 1023) bsum[nb] = sd[1023];
}
__global__ void scan3_k(int* __restrict__ rowptr, const int* __restrict__ bsum,
                        int* __restrict__ cursor, int n, int nb) {
  int i = blockIdx.x * blockDim.x + threadIdx.x;
  if (i < n) {
    int v = rowptr[i] + bsum[i >> 10];
    rowptr[i] = v;
    cursor[i] = v;
  }
  if (i == 0) rowptr[n] = bsum[nb];
}

// ---------------- fused: bf16-MFMA gemm (blocks < gb) | CSR fill (blocks >= gb) ----------
__global__ __launch_bounds__(256) void gemmfill_k(const void* __restrict__ xv,
                                                  const int* __restrict__ flag,
                                                  const unsigned short* __restrict__ bpack,
                                                  unsigned short* __restrict__ h,
                                                  const int* __restrict__ ei,
                                                  int* __restrict__ cursor,
                                                  int* __restrict__ csr_src,
                                                  int n, int e, int gb) {
  int b = blockIdx.x;
  if (b < gb) {
    int t = threadIdx.x;
    int wave = t >> 6, l = t & 63;
    int quad = l >> 4, m16 = l & 15;
    long n0 = (long)b * 128 + wave * 32;
    int isf32 = *flag;

    floatx4 acc[2][8];
#pragma unroll
    for (int mt = 0; mt < 2; mt++)
#pragma unroll
      for (int nt = 0; nt < 8; nt++) acc[mt][nt] = (floatx4){0.f, 0.f, 0.f, 0.f};

    for (int kb = 0; kb < 8; kb++) {
      short8 afr[2];
#pragma unroll
      for (int mt = 0; mt < 2; mt++) {
        long row = n0 + mt * 16 + m16;
        if (row >= n) row = n - 1;  // clamp; result discarded at store
        if (isf32) {
          const float* xp = (const float*)xv + (row << 8) + (kb << 5) + (quad << 3);
          float4 u0 = *(const float4*)xp;
          float4 u1 = *(const float4*)(xp + 4);
          short8 a;
          a[0] = (short)f2bf(u0.x); a[1] = (short)f2bf(u0.y);
          a[2] = (short)f2bf(u0.z); a[3] = (short)f2bf(u0.w);
          a[4] = (short)f2bf(u1.x); a[5] = (short)f2bf(u1.y);
          a[6] = (short)f2bf(u1.z); a[7] = (short)f2bf(u1.w);
          afr[mt] = a;
        } else {
          afr[mt] = *(const short8*)((const unsigned short*)xv + (row << 8) + (kb << 5) + (quad << 3));
        }
      }
#pragma unroll
      for (int nt = 0; nt < 8; nt++) {
        short8 bfr = *(const short8*)(bpack + (((kb << 3) + nt) << 9) + (l << 3));
        acc[0][nt] = __builtin_amdgcn_mfma_f32_16x16x32_bf16(afr[0], bfr, acc[0][nt], 0, 0, 0);
        acc[1][nt] = __builtin_amdgcn_mfma_f32_16x16x32_bf16(afr[1], bfr, acc[1][nt], 0, 0, 0);
      }
    }
#pragma unroll
    for (int mt = 0; mt < 2; mt++)
#pragma unroll
      for (int r = 0; r < 4; r++) {
        long row = n0 + mt * 16 + quad * 4 + r;
        if (row < n) {
#pragma unroll
          for (int nt = 0; nt < 8; nt++)
            h[(row << 7) + (nt << 4) + m16] = f2bf(acc[mt][nt][r]);
        }
      }
  } else {
    int i = (b - gb) * 256 + threadIdx.x;
    if (i >= e) return;
    int s = ei[i];
    unsigned d = (unsigned)ei[e + i];
    if (d >= (unsigned)n) return;
    if ((unsigned)s >= (unsigned)n) s = 0;
    int slot = atomicAdd(&cursor[d], 1);
    if ((unsigned)slot < (unsigned)e) csr_src[slot] = s;
  }
}

// ---------------- per-node attention logits (vectorized) ----------------
__global__ void att2_k(const unsigned short* __restrict__ h, const float* __restrict__ att_f,
                       float* __restrict__ a_src, float* __restrict__ a_dst, int n) {
  int idx = blockIdx.x * blockDim.x + threadIdx.x;
  if (idx >= (n << 2)) return;
  int node = idx >> 2, head = idx & 3;
  const unsigned short* hp = h + (((size_t)node) << 7) + (head << 5);
  const float* ap = att_f + (head << 6);
  float s = 0.f, d = 0.f;
#pragma unroll
  for (int q = 0; q < 4; q++) {
    uint4 raw = *(const uint4*)(hp + (q << 3));
    unsigned u[4] = {raw.x, raw.y, raw.z, raw.w};
#pragma unroll
    for (int k2 = 0; k2 < 4; k2++) {
      float v0 = bf2f((unsigned short)(u[k2] & 0xffffu));
      float v1 = bf2f((unsigned short)(u[k2] >> 16));
      int cc = (q << 3) + (k2 << 1);
      s = fmaf(v0, ap[cc], s);      s = fmaf(v1, ap[cc + 1], s);
      d = fmaf(v0, ap[32 + cc], d); d = fmaf(v1, ap[33 + cc], d);
    }
  }
  a_src[idx] = s;
  a_dst[idx] = d;
}

// ---------------- wave-per-node online-softmax aggregate; 16B/lane gather ----------------
// Gather phase: quarter q (=l>>4) handles edge slot 4*js+q; lane covers cols (l&15)*8..+7.
__global__ __launch_bounds__(256) void agg_k(const unsigned short* __restrict__ hfeat,
                                             const int* __restrict__ rowptr,
                                             const int* __restrict__ csr_src,
                                             const float* __restrict__ a_src,
                                             const float* __restrict__ a_dst,
                                             const float* __restrict__ bias_f,
                                             const int* __restrict__ flag,
                                             void* __restrict__ outv, int n) {
  int wave = threadIdx.x >> 6;
  int l = threadIdx.x & 63;
  int node = (blockIdx.x << 2) + wave;
  if (node >= n) return;
  int row0 = rowptr[node], row1 = rowptr[node + 1];
  int hq = l & 3;          // weight-phase head (slot l>>2)
  int c8 = l & 15;         // gather col group
  int hg = c8 >> 2;        // gather-phase head = (c8*8)>>5
  int q = l >> 4;          // quarter
  float4 ad4 = *(const float4*)&a_dst[node << 2];
  float adq = (hq == 0) ? ad4.x : (hq == 1) ? ad4.y : (hq == 2) ? ad4.z : ad4.w;

  float m_run = -3.0e38f;
  float swacc = 0.f;
  float acc[8];
#pragma unroll
  for (int k = 0; k < 8; k++) acc[k] = 0.f;

  for (int c0 = row0; c0 < row1; c0 += 16) {
    int cnt = min(16, row1 - c0);
    int srcv = 0;
    if (l < 16 && (c0 + l) < row1) srcv = csr_src[c0 + l];
    int myslot = l >> 2;
    int ss = __shfl(srcv, myslot, 64);
    float z = -3.0e38f;
    if (myslot < cnt) {
      float zz = a_src[(ss << 2) + hq] + adq;
      z = zz > 0.f ? zz : NEG_SLOPE * zz;
    }
    float cm = z;
    cm = fmaxf(cm, __shfl_xor(cm, 4, 64));
    cm = fmaxf(cm, __shfl_xor(cm, 8, 64));
    cm = fmaxf(cm, __shfl_xor(cm, 16, 64));
    cm = fmaxf(cm, __shfl_xor(cm, 32, 64));
    float m_new = fmaxf(m_run, cm);
    float resc_q = __expf(m_run - m_new);
    m_run = m_new;
    float wexp = (myslot < cnt) ? __expf(z - m_new) : 0.f;
    swacc = swacc * resc_q + wexp;
    float resc_h = __shfl(resc_q, hg, 64);  // lanes 0..3 hold heads 0..3
#pragma unroll
    for (int k = 0; k < 8; k++) acc[k] *= resc_h;
#pragma unroll
    for (int js = 0; js < 4; js++) {
      if ((js << 2) < cnt) {
        int eidx = (js << 2) + q;
        float sw = __shfl(wexp, (eidx << 2) | hg, 64);  // 0 for eidx >= cnt
        int sj = __shfl(srcv, eidx, 64);                // row 0 for invalid -> sw=0
        uint4 hv = *(const uint4*)(hfeat + (((size_t)sj) << 7) + (c8 << 3));
        unsigned uu[4] = {hv.x, hv.y, hv.z, hv.w};
#pragma unroll
        for (int k2 = 0; k2 < 4; k2++) {
          acc[2 * k2]     = fmaf(sw, bf2f((unsigned short)(uu[k2] & 0xffffu)), acc[2 * k2]);
          acc[2 * k2 + 1] = fmaf(sw, bf2f((unsigned short)(uu[k2] >> 16)), acc[2 * k2 + 1]);
        }
      }
    }
  }
  // per-head exp-sum over the 16 lanes sharing hq
  for (int m = 4; m < 64; m <<= 1) swacc += __shfl_xor(swacc, m, 64);
  // cross-quarter accumulator reduce
#pragma unroll
  for (int k = 0; k < 8; k++) {
    acc[k] += __shfl_xor(acc[k], 16, 64);
    acc[k] += __shfl_xor(acc[k], 32, 64);
  }
  float sumv = __shfl(swacc, hg, 64);
  float rs = 1.f / (sumv + EPSF);
  if (l < 16) {
    float o[8];
#pragma unroll
    for (int k = 0; k < 8; k++) o[k] = fmaf(acc[k], rs, bias_f[(c8 << 3) + k]);
    size_t base = (((size_t)node) << 7) + (c8 << 3);
    if (*flag) {
      *(float4*)((float*)outv + base)     = make_float4(o[0], o[1], o[2], o[3]);
      *(float4*)((float*)outv + base + 4) = make_float4(o[4], o[5], o[6], o[7]);
    } else {
      uint4 pk;
      pk.x = (unsigned)f2bf(o[0]) | ((unsigned)f2bf(o[1]) << 16);
      pk.y = (unsigned)f2bf(o[2]) | ((unsigned)f2bf(o[3]) << 16);
      pk.z = (unsigned)f2bf(o[4]) | ((unsigned)f2bf(o[5]) << 16);
      pk.w = (unsigned)f2bf(o[6]) | ((unsigned)f2bf(o[7]) << 16);
      *(uint4*)((unsigned short*)outv + base) = pk;
    }
  }
}

extern "C" void kernel_launch(void* const* d_in, const int* in_sizes, int n_in,
                              void* d_out, int out_size, void* d_ws, size_t ws_size,
                              hipStream_t stream) {
  const void* x    = d_in[0];
  const int*  ei   = (const int*)d_in[1];
  const void* w    = d_in[2];
  const void* att  = d_in[3];
  const void* bias = d_in[4];

  const int n = in_sizes[0] / 256;
  const int e = in_sizes[1] / 2;
  const int nb = (n + 1023) >> 10;
  const int hb = (e + 255) / 256;            // hist blocks
  const int gb = (n + 127) / 128;            // gemm blocks
  const int fb = (e + 255) / 256;            // fill blocks

  char* p = (char*)d_ws;
  size_t off = 0;
  auto carve = [&](size_t bytes) -> void* {
    void* r = p + off;
    off = (off + bytes + 255) & ~(size_t)255;
    return r;
  };
  int*      flag   = (int*)carve(sizeof(int));
  float*    att_f  = (float*)carve(256 * 4);
  float*    bias_f = (float*)carve(128 * 4);
  unsigned short* h = (unsigned short*)carve((size_t)n * 128 * 2);   // 12.8 MB
  float*    a_src  = (float*)carve((size_t)n * 4 * 4);
  float*    a_dst  = (float*)carve((size_t)n * 4 * 4);
  int*      deg    = (int*)carve((size_t)n * 4);
  int*      rowptr = (int*)carve((size_t)(n + 1) * 4);
  int*      cursor = (int*)carve((size_t)n * 4);
  int*      bsum   = (int*)carve((size_t)(nb + 1) * 4);
  int*      csr_src = (int*)carve((size_t)e * 4);                    // 3.2 MB
  unsigned short* bpack = (unsigned short*)carve((size_t)256 * 128 * 2);  // 64 KB
  (void)ws_size;

  prep0_k<<<(n + 255) / 256, 256, 0, stream>>>((const unsigned short*)x, flag, deg, n);
  histprep_k<<<hb + 129, 256, 0, stream>>>(ei, deg, w, att, bias, flag,
                                           bpack, att_f, bias_f, e, n, hb);
  scan1_k<<<nb, 1024, 0, stream>>>(deg, rowptr, bsum, n);
  scan2_k<<<1, 1024, 0, stream>>>(bsum, nb);
  scan3_k<<<(n + 255) / 256, 256, 0, stream>>>(rowptr, bsum, cursor, n, nb);
  gemmfill_k<<<gb + fb, 256, 0, stream>>>(x, flag, bpack, h, ei, cursor, csr_src,
                                          n, e, gb);
  att2_k<<<(n * 4 + 255) / 256, 256, 0, stream>>>(h, att_f, a_src, a_dst, n);
  agg_k<<<(n + 3) / 4, 256, 0, stream>>>(h, rowptr, csr_src, a_src, a_dst,
                                         bias_f, flag, d_out, n);
}

// Round 8
// 202.707 us; speedup vs baseline: 2.1903x; 1.2013x over previous
//
#include <hip/hip_runtime.h>
#include <hip/hip_bf16.h>

#define NEG_SLOPE 0.2f
#define EPSF 1e-16f

typedef __attribute__((ext_vector_type(8))) short short8;     // 8 bf16 = 4 VGPR
typedef __attribute__((ext_vector_type(4))) float floatx4;    // MFMA acc

__device__ __forceinline__ float bf2f(unsigned short u) {
  union { unsigned int i; float f; } v; v.i = ((unsigned int)u) << 16; return v.f;
}
__device__ __forceinline__ unsigned short f2bf(float f) {
  union { float f; unsigned int i; } v; v.f = f;
  unsigned int r = v.i + 0x7fffu + ((v.i >> 16) & 1u);  // RNE
  return (unsigned short)(r >> 16);
}

// ---------------- prep0: dtype detect (block 0) + zero cursor/ovf_cnt ----------------
__global__ void prep0_k(const unsigned short* __restrict__ xw, int* __restrict__ flag,
                        int* __restrict__ cursor, int* __restrict__ ovf_cnt, int n) {
  int i = blockIdx.x * blockDim.x + threadIdx.x;
  if (i < n) cursor[i] = 0;
  if (i == 0) *ovf_cnt = 0;
  if (blockIdx.x == 0) {
    __shared__ int cnt;
    if (threadIdx.x == 0) cnt = 0;
    __syncthreads();
    int local = 0;
    for (int k = 0; k < 16; k++) {
      unsigned short u = xw[(threadIdx.x * 16 + k) << 1];
      int ex = (u >> 7) & 0xFF;
      if (ex >= 0x90 || ex <= 0x40) local++;
    }
    atomicAdd(&cnt, local);
    __syncthreads();
    if (threadIdx.x == 0) *flag = (cnt > 256) ? 1 : 0;  // 1 = fp32 inputs
  }
}

// ---------------- prep1: B-pack (0..127) | wa=W·att pack (128..143) | bias (144) --------
__global__ __launch_bounds__(256) void prep1_k(const void* __restrict__ w,
                                               const void* __restrict__ att,
                                               const void* __restrict__ bias,
                                               const int* __restrict__ flag,
                                               unsigned short* __restrict__ bpack,
                                               unsigned short* __restrict__ wpack,
                                               float* __restrict__ bias_f) {
  int f32 = *flag;
  int pb = blockIdx.x;
  if (pb < 128) {
    int i = pb * 256 + threadIdx.x;  // 0..32767
    int j = i & 7, lane = (i >> 3) & 63, nt = (i >> 9) & 7, kb = i >> 12;
    int f = (kb << 5) + ((lane >> 4) << 3) + j;
    int col = (nt << 4) + (lane & 15);
    int src = ((col >> 5) << 13) + (f << 5) + (col & 31);
    float v = f32 ? ((const float*)w)[src] : bf2f(((const unsigned short*)w)[src]);
    bpack[i] = f2bf(v);
  } else if (pb < 144) {
    int i = (pb - 128) * 256 + threadIdx.x;  // 0..4095
    int j = i & 7, lane = (i >> 3) & 63, kb = i >> 9;
    int quad = lane >> 4, m16 = lane & 15;
    int f = (kb << 5) + (quad << 3) + j;
    float v = 0.f;
    if (m16 < 8) {
      int hd = m16 & 3;
      int db = (m16 >= 4) ? 32 : 0;
      int wbase = (hd << 13) + (f << 5);
      int abase = (hd << 6) + db;
      float acc = 0.f;
      for (int c = 0; c < 32; c++) {
        float wv = f32 ? ((const float*)w)[wbase + c] : bf2f(((const unsigned short*)w)[wbase + c]);
        float av = f32 ? ((const float*)att)[abase + c] : bf2f(((const unsigned short*)att)[abase + c]);
        acc = fmaf(wv, av, acc);
      }
      v = acc;
    }
    wpack[i] = f2bf(v);
  } else {
    int i = threadIdx.x;
    if (i < 128) bias_f[i] = f32 ? ((const float*)bias)[i] : bf2f(((const unsigned short*)bias)[i]);
  }
}

// ---------------- fused: bf16-MFMA gemm+attlogits (blocks < gb) | cap-slot fill --------
__global__ __launch_bounds__(256) void gemmfill_k(const void* __restrict__ xv,
                                                  const int* __restrict__ flag,
                                                  const unsigned short* __restrict__ bpack,
                                                  const unsigned short* __restrict__ wpack,
                                                  unsigned short* __restrict__ h,
                                                  float* __restrict__ a_srcp,
                                                  float* __restrict__ a_dstp,
                                                  const int* __restrict__ ei,
                                                  int* __restrict__ cursor,
                                                  int* __restrict__ ed,
                                                  int2* __restrict__ ovf,
                                                  int* __restrict__ ovf_cnt,
                                                  int n, int e, int gb) {
  int b = blockIdx.x;
  if (b < gb) {
    int t = threadIdx.x;
    int wave = t >> 6, l = t & 63;
    int quad = l >> 4, m16 = l & 15;
    long n0 = (long)b * 128 + wave * 32;
    int isf32 = *flag;

    floatx4 acc[2][8];
    floatx4 acca[2];
#pragma unroll
    for (int mt = 0; mt < 2; mt++) {
      acca[mt] = (floatx4){0.f, 0.f, 0.f, 0.f};
#pragma unroll
      for (int nt = 0; nt < 8; nt++) acc[mt][nt] = (floatx4){0.f, 0.f, 0.f, 0.f};
    }

    for (int kb = 0; kb < 8; kb++) {
      short8 afr[2];
#pragma unroll
      for (int mt = 0; mt < 2; mt++) {
        long row = n0 + mt * 16 + m16;
        if (row >= n) row = n - 1;  // clamp; result discarded at store
        if (isf32) {
          const float* xp = (const float*)xv + (row << 8) + (kb << 5) + (quad << 3);
          float4 u0 = *(const float4*)xp;
          float4 u1 = *(const float4*)(xp + 4);
          short8 a;
          a[0] = (short)f2bf(u0.x); a[1] = (short)f2bf(u0.y);
          a[2] = (short)f2bf(u0.z); a[3] = (short)f2bf(u0.w);
          a[4] = (short)f2bf(u1.x); a[5] = (short)f2bf(u1.y);
          a[6] = (short)f2bf(u1.z); a[7] = (short)f2bf(u1.w);
          afr[mt] = a;
        } else {
          afr[mt] = *(const short8*)((const unsigned short*)xv + (row << 8) + (kb << 5) + (quad << 3));
        }
      }
      short8 wfr = *(const short8*)(wpack + (((kb << 6) + l) << 3));
      acca[0] = __builtin_amdgcn_mfma_f32_16x16x32_bf16(afr[0], wfr, acca[0], 0, 0, 0);
      acca[1] = __builtin_amdgcn_mfma_f32_16x16x32_bf16(afr[1], wfr, acca[1], 0, 0, 0);
#pragma unroll
      for (int nt = 0; nt < 8; nt++) {
        short8 bfr = *(const short8*)(bpack + (((kb << 3) + nt) << 9) + (l << 3));
        acc[0][nt] = __builtin_amdgcn_mfma_f32_16x16x32_bf16(afr[0], bfr, acc[0][nt], 0, 0, 0);
        acc[1][nt] = __builtin_amdgcn_mfma_f32_16x16x32_bf16(afr[1], bfr, acc[1][nt], 0, 0, 0);
      }
    }
    // epilogue: C/D layout col = l&15, row = quad*4 + r
#pragma unroll
    for (int mt = 0; mt < 2; mt++)
#pragma unroll
      for (int r = 0; r < 4; r++) {
        long row = n0 + mt * 16 + quad * 4 + r;
        if (row < n) {
#pragma unroll
          for (int nt = 0; nt < 8; nt++)
            h[(row << 7) + (nt << 4) + m16] = f2bf(acc[mt][nt][r]);
          if (m16 < 8) {
            float val = acca[mt][r];
            int hd = m16 & 3;
            if (m16 < 4) a_srcp[(row << 2) + hd] = val;
            else         a_dstp[(row << 2) + hd] = val;
          }
        }
      }
  } else {
    int i = (b - gb) * 256 + threadIdx.x;
    if (i >= e) return;
    int s = ei[i];
    unsigned d = (unsigned)ei[e + i];
    if (d >= (unsigned)n) return;
    if ((unsigned)s >= (unsigned)n) s = 0;
    int c = atomicAdd(&cursor[d], 1);
    if (c < 32) {
      ed[((int)d << 5) + c] = s;
    } else {
      int k = atomicAdd(ovf_cnt, 1);
      if (k < e) ovf[k] = make_int2((int)d, s);
    }
  }
}

// ---------------- wave-per-node online-softmax aggregate; 16B/lane gather ----------------
__global__ __launch_bounds__(256) void agg_k(const unsigned short* __restrict__ hfeat,
                                             const int* __restrict__ cursor,
                                             const int* __restrict__ ed,
                                             const int2* __restrict__ ovf,
                                             const int* __restrict__ ovf_cnt,
                                             const float* __restrict__ a_src,
                                             const float* __restrict__ a_dst,
                                             const float* __restrict__ bias_f,
                                             const int* __restrict__ flag,
                                             void* __restrict__ outv, int n, int e) {
  int wave = threadIdx.x >> 6;
  int l = threadIdx.x & 63;
  int node = (blockIdx.x << 2) + wave;
  if (node >= n) return;
  int total = cursor[node];
  int cnt0 = min(total, 32);
  int hq = l & 3;          // weight-phase head (slot l>>2)
  int c8 = l & 15;         // gather col group
  int hg = c8 >> 2;        // gather-phase head
  int q = l >> 4;          // quarter
  float4 ad4 = *(const float4*)&a_dst[node << 2];
  float adq = (hq == 0) ? ad4.x : (hq == 1) ? ad4.y : (hq == 2) ? ad4.z : ad4.w;

  float m_run = -3.0e38f;
  float swacc = 0.f;
  float acc[8];
#pragma unroll
  for (int k = 0; k < 8; k++) acc[k] = 0.f;

  // ---- in-slot chunks (<=2) ----
  for (int c0 = 0; c0 < cnt0; c0 += 16) {
    int cnt = min(16, cnt0 - c0);
    int srcv = 0;
    if (l < 16 && (c0 + l) < cnt0) srcv = ed[(node << 5) + c0 + l];
    int myslot = l >> 2;
    int ss = __shfl(srcv, myslot, 64);
    float z = -3.0e38f;
    if (myslot < cnt) {
      float zz = a_src[(ss << 2) + hq] + adq;
      z = zz > 0.f ? zz : NEG_SLOPE * zz;
    }
    float cm = z;
    cm = fmaxf(cm, __shfl_xor(cm, 4, 64));
    cm = fmaxf(cm, __shfl_xor(cm, 8, 64));
    cm = fmaxf(cm, __shfl_xor(cm, 16, 64));
    cm = fmaxf(cm, __shfl_xor(cm, 32, 64));
    float m_new = fmaxf(m_run, cm);
    float resc_q = __expf(m_run - m_new);
    m_run = m_new;
    float wexp = (myslot < cnt) ? __expf(z - m_new) : 0.f;
    swacc = swacc * resc_q + wexp;
    float resc_h = __shfl(resc_q, hg, 64);
#pragma unroll
    for (int k = 0; k < 8; k++) acc[k] *= resc_h;
#pragma unroll
    for (int js = 0; js < 4; js++) {
      if ((js << 2) < cnt) {
        int eidx = (js << 2) + q;
        float sw = __shfl(wexp, (eidx << 2) | hg, 64);
        int sj = __shfl(srcv, eidx, 64);
        uint4 hv = *(const uint4*)(hfeat + (((size_t)sj) << 7) + (c8 << 3));
        unsigned uu[4] = {hv.x, hv.y, hv.z, hv.w};
#pragma unroll
        for (int k2 = 0; k2 < 4; k2++) {
          acc[2 * k2]     = fmaf(sw, bf2f((unsigned short)(uu[k2] & 0xffffu)), acc[2 * k2]);
          acc[2 * k2 + 1] = fmaf(sw, bf2f((unsigned short)(uu[k2] >> 16)), acc[2 * k2 + 1]);
        }
      }
    }
  }

  // ---- overflow scan (rare: only nodes with degree > 32) ----
  if (total > 32) {
    int K = *ovf_cnt;
    if (K > e) K = e;
    for (int c0 = 0; c0 < K; c0 += 16) {
      int sv = 0, dv = -1;
      if (l < 16 && (c0 + l) < K) { int2 pr = ovf[c0 + l]; dv = pr.x; sv = pr.y; }
      int myslot = l >> 2;
      int dmy = __shfl(dv, myslot, 64);
      int smy = __shfl(sv, myslot, 64);
      bool valid = (dmy == node);
      float z = -3.0e38f;
      if (valid) {
        float zz = a_src[(smy << 2) + hq] + adq;
        z = zz > 0.f ? zz : NEG_SLOPE * zz;
      }
      float cm = z;
      cm = fmaxf(cm, __shfl_xor(cm, 4, 64));
      cm = fmaxf(cm, __shfl_xor(cm, 8, 64));
      cm = fmaxf(cm, __shfl_xor(cm, 16, 64));
      cm = fmaxf(cm, __shfl_xor(cm, 32, 64));
      float m_new = fmaxf(m_run, cm);
      float resc_q = __expf(m_run - m_new);
      m_run = m_new;
      float wexp = valid ? __expf(z - m_new) : 0.f;
      swacc = swacc * resc_q + wexp;
      float resc_h = __shfl(resc_q, hg, 64);
#pragma unroll
      for (int k = 0; k < 8; k++) acc[k] *= resc_h;
#pragma unroll
      for (int js = 0; js < 4; js++) {
        int eidx = (js << 2) + q;
        float sw = __shfl(wexp, (eidx << 2) | hg, 64);
        int sj = __shfl(sv, eidx, 64);
        uint4 hv = *(const uint4*)(hfeat + (((size_t)sj) << 7) + (c8 << 3));
        unsigned uu[4] = {hv.x, hv.y, hv.z, hv.w};
#pragma unroll
        for (int k2 = 0; k2 < 4; k2++) {
          acc[2 * k2]     = fmaf(sw, bf2f((unsigned short)(uu[k2] & 0xffffu)), acc[2 * k2]);
          acc[2 * k2 + 1] = fmaf(sw, bf2f((unsigned short)(uu[k2] >> 16)), acc[2 * k2 + 1]);
        }
      }
    }
  }

  // per-head exp-sum over the 16 lanes sharing hq
  for (int m = 4; m < 64; m <<= 1) swacc += __shfl_xor(swacc, m, 64);
  // cross-quarter accumulator reduce
#pragma unroll
  for (int k = 0; k < 8; k++) {
    acc[k] += __shfl_xor(acc[k], 16, 64);
    acc[k] += __shfl_xor(acc[k], 32, 64);
  }
  float sumv = __shfl(swacc, hg, 64);
  float rs = 1.f / (sumv + EPSF);
  if (l < 16) {
    float o[8];
#pragma unroll
    for (int k = 0; k < 8; k++) o[k] = fmaf(acc[k], rs, bias_f[(c8 << 3) + k]);
    size_t base = (((size_t)node) << 7) + (c8 << 3);
    if (*flag) {
      *(float4*)((float*)outv + base)     = make_float4(o[0], o[1], o[2], o[3]);
      *(float4*)((float*)outv + base + 4) = make_float4(o[4], o[5], o[6], o[7]);
    } else {
      uint4 pk;
      pk.x = (unsigned)f2bf(o[0]) | ((unsigned)f2bf(o[1]) << 16);
      pk.y = (unsigned)f2bf(o[2]) | ((unsigned)f2bf(o[3]) << 16);
      pk.z = (unsigned)f2bf(o[4]) | ((unsigned)f2bf(o[5]) << 16);
      pk.w = (unsigned)f2bf(o[6]) | ((unsigned)f2bf(o[7]) << 16);
      *(uint4*)((unsigned short*)outv + base) = pk;
    }
  }
}

extern "C" void kernel_launch(void* const* d_in, const int* in_sizes, int n_in,
                              void* d_out, int out_size, void* d_ws, size_t ws_size,
                              hipStream_t stream) {
  const void* x    = d_in[0];
  const int*  ei   = (const int*)d_in[1];
  const void* w    = d_in[2];
  const void* att  = d_in[3];
  const void* bias = d_in[4];

  const int n = in_sizes[0] / 256;
  const int e = in_sizes[1] / 2;
  const int gb = (n + 127) / 128;            // gemm blocks
  const int fb = (e + 255) / 256;            // fill blocks

  char* p = (char*)d_ws;
  size_t off = 0;
  auto carve = [&](size_t bytes) -> void* {
    void* r = p + off;
    off = (off + bytes + 255) & ~(size_t)255;
    return r;
  };
  int*      flag    = (int*)carve(sizeof(int));
  int*      ovf_cnt = (int*)carve(sizeof(int));
  float*    bias_f  = (float*)carve(128 * 4);
  unsigned short* h = (unsigned short*)carve((size_t)n * 128 * 2);   // 12.8 MB
  float*    a_src   = (float*)carve((size_t)n * 4 * 4);
  float*    a_dst   = (float*)carve((size_t)n * 4 * 4);
  int*      cursor  = (int*)carve((size_t)n * 4);
  int*      ed      = (int*)carve((size_t)n * 32 * 4);               // 6.4 MB
  int2*     ovf     = (int2*)carve((size_t)e * 8);                   // 6.4 MB
  unsigned short* bpack = (unsigned short*)carve((size_t)256 * 128 * 2);  // 64 KB
  unsigned short* wpack = (unsigned short*)carve((size_t)8 * 64 * 8 * 2); // 8 KB
  (void)ws_size;

  prep0_k<<<(n + 255) / 256, 256, 0, stream>>>((const unsigned short*)x, flag,
                                               cursor, ovf_cnt, n);
  prep1_k<<<145, 256, 0, stream>>>(w, att, bias, flag, bpack, wpack, bias_f);
  gemmfill_k<<<gb + fb, 256, 0, stream>>>(x, flag, bpack, wpack, h, a_src, a_dst,
                                          ei, cursor, ed, ovf, ovf_cnt, n, e, gb);
  agg_k<<<(n + 3) / 4, 256, 0, stream>>>(h, cursor, ed, ovf, ovf_cnt, a_src, a_dst,
                                         bias_f, flag, d_out, n, e);
}